// Round 1
// baseline (2378.103 us; speedup 1.0000x reference)
//
#include <hip/hip_runtime.h>

// Problem constants (fixed by the reference)
#define M 3
#define B 32
#define S 256
#define D 768
#define H 1024
#define MD (M * D)          // 2304
#define NP (M * (M - 1))    // 6 ordered (i,j) pairs, p = i*2 + c, j = c + (c>=i)
#define SCALE 0.03608439182435161f  // 1/sqrt(768)
#define LN_EPS 1e-5f

// Workspace layout (float offsets). Total 773697 floats = ~3.1 MB.
#define OFF_WMU   0         // [M][D]   Wq[i] @ mu_w[i]
#define OFF_WLV   2304      // [M][D]   Wq[i] @ lv_w[i]
#define OFF_WPGQ  4608      // [M][D]   Wq[i] @ pgq_w[i]
#define OFF_WPK   6912      // [NP][D]  Wk[j] @ pgk_w[i]
#define OFF_CMU   11520     // [M]
#define OFF_CLV   11523     // [M]
#define OFF_CPGQ  11526     // [M]
#define OFF_CPK   11529     // [NP]
#define OFF_MU    11552     // [M][B][S]
#define OFF_LV    36128     // [M][B][S]
#define OFF_PKPRE 60704     // [NP][B][S]
#define OFF_PQPRE 109856    // [M][B]
#define OFF_Q     109952    // [M][B][D]   q row at s=0 (incl. bq)
#define OFF_QBK   183680    // [NP][B]     q . bk[j]
#define OFF_QK    183872    // [NP][B][D]  Wk[j] @ q
#define OFF_FSUM  331328    // [NP][B][D]  softmax-weighted feats sum
#define OFF_AGG   478784    // [M][B][D]
#define OFF_E     552512    // [M][B][D]
#define OFF_G     626240    // [M][B][D]
#define OFF_FUSED 699968    // [B][MD]
#define OFF_KL    773696    // [1]

__device__ __forceinline__ float wave_reduce(float v) {
    #pragma unroll
    for (int o = 32; o > 0; o >>= 1) v += __shfl_down(v, o, 64);
    return v;
}

__device__ __forceinline__ float sigmoidf(float x) {
    return 1.0f / (1.0f + __expf(-x));
}

// K0a: w_mu[i] = Wq[i]@mu_w[i], etc; w_pk[p] = Wk[j]@pgk_w[i]. 15 blocks.
__global__ __launch_bounds__(256) void k_vecs(const float* Wq, const float* Wk,
        const float* mu_w, const float* lv_w, const float* pgq_w, const float* pgk_w,
        float* ws) {
    int job = blockIdx.x;  // 0..14
    const float* Wm; const float* v; float* out;
    if (job < 9) {
        int type = job / 3, i = job % 3;
        Wm = Wq + i * D * D;
        v = (type == 0 ? mu_w : type == 1 ? lv_w : pgq_w) + i * D;
        out = ws + (type == 0 ? OFF_WMU : type == 1 ? OFF_WLV : OFF_WPGQ) + i * D;
    } else {
        int p = job - 9, i = p / 2, c = p % 2, j = c + (c >= i ? 1 : 0);
        Wm = Wk + j * D * D; v = pgk_w + i * D; out = ws + OFF_WPK + p * D;
    }
    __shared__ float vs[D];
    for (int t = threadIdx.x; t < D; t += 256) vs[t] = v[t];
    __syncthreads();
    int wave = threadIdx.x >> 6, lane = threadIdx.x & 63;
    for (int d = wave; d < D; d += 4) {
        const float* row = Wm + d * D;
        float acc = 0.f;
        for (int t = lane; t < D; t += 64) acc += row[t] * vs[t];
        acc = wave_reduce(acc);
        if (lane == 0) out[d] = acc;
    }
}

// K0b: scalar constants. 1 block.
__global__ __launch_bounds__(256) void k_scalars(const float* bq, const float* bk,
        const float* mu_w, const float* mu_b, const float* lv_w, const float* lv_b,
        const float* pgq_w, const float* pgq_b, const float* pgk_w, const float* pgk_b,
        float* ws) {
    int wave = threadIdx.x >> 6, lane = threadIdx.x & 63;
    for (int job = wave; job < 15; job += 4) {
        const float* a; const float* bvec; float bias; float* out;
        if (job < 3)      { int i = job;     a = bq + i * D; bvec = mu_w + i * D;  bias = mu_b[i];  out = ws + OFF_CMU + i; }
        else if (job < 6) { int i = job - 3; a = bq + i * D; bvec = lv_w + i * D;  bias = lv_b[i];  out = ws + OFF_CLV + i; }
        else if (job < 9) { int i = job - 6; a = bq + i * D; bvec = pgq_w + i * D; bias = pgq_b[i]; out = ws + OFF_CPGQ + i; }
        else {
            int p = job - 9, i = p / 2, c = p % 2, j = c + (c >= i ? 1 : 0);
            a = bk + j * D; bvec = pgk_w + i * D; bias = pgk_b[i]; out = ws + OFF_CPK + p;
        }
        float acc = 0.f;
        for (int t = lane; t < D; t += 64) acc += a[t] * bvec[t];
        acc = wave_reduce(acc);
        if (lane == 0) *out = acc + bias;
    }
}

// K1: one full pass over feats: mu/lv/pkpre/pqpre + KL. 6144 blocks (4 rows each).
__global__ __launch_bounds__(256) void k_stats(const float* feats, float* ws) {
    int wave = threadIdx.x >> 6, lane = threadIdx.x & 63;
    int row = blockIdx.x * 4 + wave;          // (m*B+b)*S+s, 0..24575
    int m = row / (B * S);
    int rem = row % (B * S);
    int b = rem / S, s = rem % S;
    const float* f = feats + row * D;
    int plist[2]; int np = 0;
    #pragma unroll
    for (int p = 0; p < NP; p++) {
        int i = p / 2, c = p % 2, j = c + (c >= i ? 1 : 0);
        if (j == m) plist[np++] = p;
    }
    const float* wmu = ws + OFF_WMU + m * D;
    const float* wlv = ws + OFF_WLV + m * D;
    const float* wpgq = ws + OFF_WPGQ + m * D;
    const float* wpk0 = ws + OFF_WPK + plist[0] * D;
    const float* wpk1 = ws + OFF_WPK + plist[1] * D;
    float amu = 0.f, alv = 0.f, apgq = 0.f, apk0 = 0.f, apk1 = 0.f;
    for (int t = lane; t < D; t += 64) {
        float x = f[t];
        amu += x * wmu[t]; alv += x * wlv[t]; apgq += x * wpgq[t];
        apk0 += x * wpk0[t]; apk1 += x * wpk1[t];
    }
    amu = wave_reduce(amu); alv = wave_reduce(alv); apgq = wave_reduce(apgq);
    apk0 = wave_reduce(apk0); apk1 = wave_reduce(apk1);
    if (lane == 0) {
        float muv = amu + ws[OFF_CMU + m];
        float lvv = alv + ws[OFF_CLV + m];
        ws[OFF_MU + row] = muv;
        ws[OFF_LV + row] = lvv;
        ws[OFF_PKPRE + (plist[0] * B + b) * S + s] = apk0 + ws[OFF_CPK + plist[0]];
        ws[OFF_PKPRE + (plist[1] * B + b) * S + s] = apk1 + ws[OFF_CPK + plist[1]];
        if (s == 0) ws[OFF_PQPRE + m * B + b] = apgq + ws[OFF_CPGQ + m];
        // kl = -sum_{m,b,s} (1 + lv - mu^2 - exp(lv))   (the j-loop double-count folds to once per row)
        float term = 1.0f + lvv - muv * muv - expf(lvv);
        atomicAdd(ws + OFF_KL, -term);
    }
}

// K2: q[i,b,:] = feats[i,b,0,:] @ Wq[i] + bq[i].  36 blocks (i, e-chunk 3, b-group 4).
__global__ __launch_bounds__(256) void k_qrow(const float* feats, const float* Wq,
                                              const float* bq, float* ws) {
    int blk = blockIdx.x;
    int i = blk / 12, r = blk % 12, ec = r / 4, bg = r % 4;
    __shared__ float xs[8][D];
    for (int bb = 0; bb < 8; bb++) {
        const float* f = feats + ((i * B + bg * 8 + bb) * S) * D;  // s = 0
        for (int t = threadIdx.x; t < D; t += 256) xs[bb][t] = f[t];
    }
    __syncthreads();
    int e = ec * 256 + threadIdx.x;
    const float* Wm = Wq + i * D * D;
    float bias = bq[i * D + e];
    float acc[8];
    #pragma unroll
    for (int bb = 0; bb < 8; bb++) acc[bb] = bias;
    for (int d = 0; d < D; d++) {
        float w = Wm[d * D + e];
        #pragma unroll
        for (int bb = 0; bb < 8; bb++) acc[bb] += xs[bb][d] * w;
    }
    #pragma unroll
    for (int bb = 0; bb < 8; bb++) ws[OFF_Q + (i * B + bg * 8 + bb) * D + e] = acc[bb];
}

// K3: qk[p,b,:] = Wk[j] @ q[i,b,:].  96 blocks (p, b-group 4, d-chunk 4); wave-reduce rows.
__global__ __launch_bounds__(256) void k_qk(const float* Wk, float* ws) {
    int blk = blockIdx.x;
    int p = blk / 16, r = blk % 16, bg = r / 4, dc = r % 4;
    int i = p / 2, c = p % 2, j = c + (c >= i ? 1 : 0);
    __shared__ float qs[8][D];
    for (int bb = 0; bb < 8; bb++) {
        const float* q = ws + OFF_Q + (i * B + bg * 8 + bb) * D;
        for (int t = threadIdx.x; t < D; t += 256) qs[bb][t] = q[t];
    }
    __syncthreads();
    int wave = threadIdx.x >> 6, lane = threadIdx.x & 63;
    const float* Wm = Wk + j * D * D;
    for (int d = dc * 192 + wave; d < dc * 192 + 192; d += 4) {
        const float* row = Wm + d * D;
        float a[8] = {0, 0, 0, 0, 0, 0, 0, 0};
        for (int t = lane; t < D; t += 64) {
            float w = row[t];
            #pragma unroll
            for (int bb = 0; bb < 8; bb++) a[bb] += w * qs[bb][t];
        }
        #pragma unroll
        for (int bb = 0; bb < 8; bb++) a[bb] = wave_reduce(a[bb]);
        if (lane == 0) {
            #pragma unroll
            for (int bb = 0; bb < 8; bb++)
                ws[OFF_QK + (p * B + bg * 8 + bb) * D + d] = a[bb];
        }
    }
}

// K3b: qbk[p,b] = q[i,b,:] . bk[j].  6 blocks.
__global__ __launch_bounds__(256) void k_qbk(const float* bk, float* ws) {
    int p = blockIdx.x;
    int i = p / 2, c = p % 2, j = c + (c >= i ? 1 : 0);
    int wave = threadIdx.x >> 6, lane = threadIdx.x & 63;
    for (int b = wave; b < B; b += 4) {
        const float* q = ws + OFF_Q + (i * B + b) * D;
        const float* bkj = bk + j * D;
        float a = 0.f;
        for (int t = lane; t < D; t += 64) a += q[t] * bkj[t];
        a = wave_reduce(a);
        if (lane == 0) ws[OFF_QBK + p * B + b] = a;
    }
}

// K4: gated attention row q=0 + softmax + weighted feats sum. 192 blocks (p,b).
__global__ __launch_bounds__(256) void k_attn(const float* feats, const float* eps,
                                              const float* dyn, float* ws) {
    int blk = blockIdx.x;
    int p = blk / B, b = blk % B;
    int i = p / 2, c = p % 2, j = c + (c >= i ? 1 : 0);
    __shared__ float qks[D];
    __shared__ float sc[S];
    __shared__ float red[256];
    __shared__ float pqs;
    for (int t = threadIdx.x; t < D; t += 256) qks[t] = ws[OFF_QK + (p * B + b) * D + t];
    float dynv = dyn[0];
    if (threadIdx.x == 0) {
        float mu0 = ws[OFF_MU + (i * B + b) * S];
        float lv0 = ws[OFF_LV + (i * B + b) * S];
        float e0 = eps[(p * B + b) * S];
        float g0 = sigmoidf(mu0 + dynv * __expf(0.5f * lv0) * e0);
        pqs = sigmoidf(ws[OFF_PQPRE + i * B + b]) * g0;
    }
    __syncthreads();
    int wave = threadIdx.x >> 6, lane = threadIdx.x & 63;
    float qbk = ws[OFF_QBK + p * B + b];
    for (int k = wave; k < S; k += 4) {
        const float* f = feats + ((j * B + b) * S + k) * D;
        float a = 0.f;
        for (int t = lane; t < D; t += 64) a += f[t] * qks[t];
        a = wave_reduce(a);
        if (lane == 0) {
            float muk = ws[OFF_MU + (i * B + b) * S + k];
            float lvk = ws[OFF_LV + (i * B + b) * S + k];
            float ek = eps[(p * B + b) * S + k];
            float g = sigmoidf(muk + dynv * __expf(0.5f * lvk) * ek);
            float pk = sigmoidf(ws[OFF_PKPRE + (p * B + b) * S + k]) * g;
            sc[k] = (a + qbk) * SCALE * pqs * pk;
        }
    }
    __syncthreads();
    int t = threadIdx.x;
    // softmax over 256 scores
    red[t] = sc[t];
    __syncthreads();
    for (int st = 128; st > 0; st >>= 1) {
        if (t < st) red[t] = fmaxf(red[t], red[t + st]);
        __syncthreads();
    }
    float mx = red[0];
    __syncthreads();
    float w = __expf(sc[t] - mx);
    red[t] = w;
    __syncthreads();
    for (int st = 128; st > 0; st >>= 1) {
        if (t < st) red[t] += red[t + st];
        __syncthreads();
    }
    float inv = 1.0f / red[0];
    __syncthreads();
    sc[t] = w * inv;
    __syncthreads();
    // weighted feats sum
    float a0 = 0.f, a1 = 0.f, a2 = 0.f;
    const float* fb = feats + ((j * B + b) * S) * D;
    for (int k = 0; k < S; k++) {
        float wk = sc[k];
        const float* f = fb + k * D;
        a0 += wk * f[t]; a1 += wk * f[t + 256]; a2 += wk * f[t + 512];
    }
    float* o = ws + OFF_FSUM + (p * B + b) * D;
    o[t] = a0; o[t + 256] = a1; o[t + 512] = a2;
}

// K5a: agg[i,b,:] = sum_c fsum[p,b,:] @ Wv[j] + bv[j]. 36 blocks.
__global__ __launch_bounds__(256) void k_agg(const float* Wv, const float* bv, float* ws) {
    int blk = blockIdx.x;
    int i = blk / 12, r = blk % 12, ec = r / 4, bg = r % 4;
    int j0 = (0 >= i ? 1 : 0);
    int j1 = 1 + (1 >= i ? 1 : 0);
    int p0 = i * 2, p1 = i * 2 + 1;
    __shared__ float f0s[8][D];
    __shared__ float f1s[8][D];
    for (int bb = 0; bb < 8; bb++) {
        const float* a = ws + OFF_FSUM + (p0 * B + bg * 8 + bb) * D;
        const float* b2 = ws + OFF_FSUM + (p1 * B + bg * 8 + bb) * D;
        for (int t = threadIdx.x; t < D; t += 256) { f0s[bb][t] = a[t]; f1s[bb][t] = b2[t]; }
    }
    __syncthreads();
    int e = ec * 256 + threadIdx.x;
    const float* W0 = Wv + j0 * D * D;
    const float* W1 = Wv + j1 * D * D;
    float bias = bv[j0 * D + e] + bv[j1 * D + e];
    float acc[8];
    #pragma unroll
    for (int bb = 0; bb < 8; bb++) acc[bb] = bias;
    for (int d = 0; d < D; d++) {
        float w0 = W0[d * D + e], w1 = W1[d * D + e];
        #pragma unroll
        for (int bb = 0; bb < 8; bb++) acc[bb] += f0s[bb][d] * w0 + f1s[bb][d] * w1;
    }
    #pragma unroll
    for (int bb = 0; bb < 8; bb++) ws[OFF_AGG + (i * B + bg * 8 + bb) * D + e] = acc[bb];
}

// K5b: E = relu(agg@WE + WE_b), G = relu(agg@Wh + Wh_b + q@Wqc + Wqc_b). 36 blocks.
__global__ __launch_bounds__(256) void k_eg(const float* WE_w, const float* WE_b,
        const float* Wh_w, const float* Wh_b, const float* Wqc_w, const float* Wqc_b,
        float* ws) {
    int blk = blockIdx.x;
    int i = blk / 12, r = blk % 12, ec = r / 4, bg = r % 4;
    __shared__ float as[8][D];
    __shared__ float qs[8][D];
    for (int bb = 0; bb < 8; bb++) {
        const float* a = ws + OFF_AGG + (i * B + bg * 8 + bb) * D;
        const float* q = ws + OFF_Q + (i * B + bg * 8 + bb) * D;
        for (int t = threadIdx.x; t < D; t += 256) { as[bb][t] = a[t]; qs[bb][t] = q[t]; }
    }
    __syncthreads();
    int e = ec * 256 + threadIdx.x;
    const float* WE = WE_w + i * D * D;
    const float* Wh = Wh_w + i * D * D;
    const float* Wq2 = Wqc_w + i * D * D;
    float eb = WE_b[i * D + e];
    float gb = Wh_b[i * D + e] + Wqc_b[i * D + e];
    float ea[8], ga[8];
    #pragma unroll
    for (int bb = 0; bb < 8; bb++) { ea[bb] = eb; ga[bb] = gb; }
    for (int d = 0; d < D; d++) {
        float we = WE[d * D + e], wh = Wh[d * D + e], wq = Wq2[d * D + e];
        #pragma unroll
        for (int bb = 0; bb < 8; bb++) {
            float av = as[bb][d];
            ea[bb] += av * we;
            ga[bb] += av * wh + qs[bb][d] * wq;
        }
    }
    #pragma unroll
    for (int bb = 0; bb < 8; bb++) {
        int idx = (i * B + bg * 8 + bb) * D + e;
        ws[OFF_E + idx] = fmaxf(ea[bb], 0.f);
        ws[OFF_G + idx] = fmaxf(ga[bb], 0.f);
    }
}

// K5c: LayerNorm(E)*LayerNorm(G) -> fused. 96 blocks (i,b).
__global__ __launch_bounds__(256) void k_ln(const float* lnE_g, const float* lnE_b,
        const float* lnG_g, const float* lnG_b, float* ws) {
    int blk = blockIdx.x;
    int i = blk / B, b = blk % B;
    const float* E = ws + OFF_E + (i * B + b) * D;
    const float* G = ws + OFF_G + (i * B + b) * D;
    int t = threadIdx.x;
    float e0 = E[t], e1 = E[t + 256], e2 = E[t + 512];
    float g0 = G[t], g1 = G[t + 256], g2 = G[t + 512];
    __shared__ float r1[256], r2[256], r3[256], r4[256];
    r1[t] = e0 + e1 + e2;
    r2[t] = e0 * e0 + e1 * e1 + e2 * e2;
    r3[t] = g0 + g1 + g2;
    r4[t] = g0 * g0 + g1 * g1 + g2 * g2;
    __syncthreads();
    for (int st = 128; st > 0; st >>= 1) {
        if (t < st) { r1[t] += r1[t + st]; r2[t] += r2[t + st]; r3[t] += r3[t + st]; r4[t] += r4[t + st]; }
        __syncthreads();
    }
    float mE = r1[0] * (1.0f / D), vE = r2[0] * (1.0f / D) - mE * mE;
    float mG = r3[0] * (1.0f / D), vG = r4[0] * (1.0f / D) - mG * mG;
    float sE = rsqrtf(vE + LN_EPS), sG = rsqrtf(vG + LN_EPS);
    float* o = ws + OFF_FUSED + b * MD + i * D;
    const float* eg = lnE_g + i * D; const float* ebv = lnE_b + i * D;
    const float* gg = lnG_g + i * D; const float* gbv = lnG_b + i * D;
    o[t]       = ((e0 - mE) * sE * eg[t]       + ebv[t])       * ((g0 - mG) * sG * gg[t]       + gbv[t]);
    o[t + 256] = ((e1 - mE) * sE * eg[t + 256] + ebv[t + 256]) * ((g1 - mG) * sG * gg[t + 256] + gbv[t + 256]);
    o[t + 512] = ((e2 - mE) * sE * eg[t + 512] + ebv[t + 512]) * ((g2 - mG) * sG * gg[t + 512] + gbv[t + 512]);
}

// K6: out = fused @ out_w + out_b; also writes kl. 32 blocks (h-chunk 4, b-group 8).
__global__ __launch_bounds__(256) void k_out(const float* out_w, const float* out_b,
                                             float* ws, float* out) {
    int blk = blockIdx.x;
    int hc = blk / 8, bg = blk % 8;
    __shared__ float xs[4][MD];
    for (int bb = 0; bb < 4; bb++) {
        const float* x = ws + OFF_FUSED + (bg * 4 + bb) * MD;
        for (int t = threadIdx.x; t < MD; t += 256) xs[bb][t] = x[t];
    }
    __syncthreads();
    int h = hc * 256 + threadIdx.x;
    float bias = out_b[h];
    float acc[4];
    #pragma unroll
    for (int bb = 0; bb < 4; bb++) acc[bb] = bias;
    for (int f = 0; f < MD; f++) {
        float w = out_w[f * H + h];
        #pragma unroll
        for (int bb = 0; bb < 4; bb++) acc[bb] += xs[bb][f] * w;
    }
    #pragma unroll
    for (int bb = 0; bb < 4; bb++) out[(bg * 4 + bb) * H + h] = acc[bb];
    if (blk == 0 && threadIdx.x == 0) out[B * H] = ws[OFF_KL];
}

extern "C" void kernel_launch(void* const* d_in, const int* in_sizes, int n_in,
                              void* d_out, int out_size, void* d_ws, size_t ws_size,
                              hipStream_t stream) {
    const float* feats = (const float*)d_in[0];
    const float* Wq    = (const float*)d_in[1];
    const float* bq    = (const float*)d_in[2];
    const float* Wk    = (const float*)d_in[3];
    const float* bk    = (const float*)d_in[4];
    const float* Wv    = (const float*)d_in[5];
    const float* bv    = (const float*)d_in[6];
    const float* pgq_w = (const float*)d_in[7];
    const float* pgq_b = (const float*)d_in[8];
    const float* pgk_w = (const float*)d_in[9];
    const float* pgk_b = (const float*)d_in[10];
    const float* mu_w  = (const float*)d_in[11];
    const float* mu_b  = (const float*)d_in[12];
    const float* lv_w  = (const float*)d_in[13];
    const float* lv_b  = (const float*)d_in[14];
    const float* dyn   = (const float*)d_in[15];
    const float* WE_w  = (const float*)d_in[16];
    const float* WE_b  = (const float*)d_in[17];
    const float* Wh_w  = (const float*)d_in[18];
    const float* Wh_b  = (const float*)d_in[19];
    const float* Wqc_w = (const float*)d_in[20];
    const float* Wqc_b = (const float*)d_in[21];
    const float* lnE_g = (const float*)d_in[22];
    const float* lnE_b = (const float*)d_in[23];
    const float* lnG_g = (const float*)d_in[24];
    const float* lnG_b = (const float*)d_in[25];
    const float* out_w = (const float*)d_in[26];
    const float* out_b = (const float*)d_in[27];
    const float* eps   = (const float*)d_in[28];
    float* ws  = (float*)d_ws;
    float* out = (float*)d_out;

    // Zero the KL accumulator (ws is poisoned 0xAA before every timed launch).
    hipMemsetAsync((char*)d_ws + OFF_KL * sizeof(float), 0, sizeof(float), stream);

    k_vecs<<<15, 256, 0, stream>>>(Wq, Wk, mu_w, lv_w, pgq_w, pgk_w, ws);
    k_scalars<<<1, 256, 0, stream>>>(bq, bk, mu_w, mu_b, lv_w, lv_b,
                                     pgq_w, pgq_b, pgk_w, pgk_b, ws);
    k_stats<<<(M * B * S) / 4, 256, 0, stream>>>(feats, ws);
    k_qrow<<<36, 256, 0, stream>>>(feats, Wq, bq, ws);
    k_qk<<<96, 256, 0, stream>>>(Wk, ws);
    k_qbk<<<NP, 256, 0, stream>>>(bk, ws);
    k_attn<<<NP * B, 256, 0, stream>>>(feats, eps, dyn, ws);
    k_agg<<<36, 256, 0, stream>>>(Wv, bv, ws);
    k_eg<<<36, 256, 0, stream>>>(WE_w, WE_b, Wh_w, Wh_b, Wqc_w, Wqc_b, ws);
    k_ln<<<M * B, 256, 0, stream>>>(lnE_g, lnE_b, lnG_g, lnG_b, ws);
    k_out<<<32, 256, 0, stream>>>(out_w, out_b, ws, out);
}

// Round 2
// 1054.953 us; speedup vs baseline: 2.2542x; 2.2542x over previous
//
#include <hip/hip_runtime.h>

// Problem constants (fixed by the reference)
#define M 3
#define B 32
#define S 256
#define D 768
#define H 1024
#define MD (M * D)          // 2304
#define NP (M * (M - 1))    // 6 ordered (i,j) pairs, p = i*2 + c, j = c + (c>=i)
#define SCALE 0.03608439182435161f  // 1/sqrt(768)
#define LN_EPS 1e-5f

// Workspace layout (float offsets). Total 773697 floats = ~3.1 MB.
#define OFF_WMU   0         // [M][D]   Wq[i] @ mu_w[i]
#define OFF_WLV   2304      // [M][D]   Wq[i] @ lv_w[i]
#define OFF_WPGQ  4608      // [M][D]   Wq[i] @ pgq_w[i]
#define OFF_WPK   6912      // [NP][D]  Wk[j] @ pgk_w[i]
#define OFF_CMU   11520     // [M]
#define OFF_CLV   11523     // [M]
#define OFF_CPGQ  11526     // [M]
#define OFF_CPK   11529     // [NP]
#define OFF_MU    11552     // [M][B][S]
#define OFF_LV    36128     // [M][B][S]
#define OFF_PKPRE 60704     // [NP][B][S]
#define OFF_PQPRE 109856    // [M][B]
#define OFF_Q     109952    // [M][B][D]   q row at s=0 (incl. bq)
#define OFF_QBK   183680    // [NP][B]     q . bk[j]
#define OFF_QK    183872    // [NP][B][D]  Wk[j] @ q
#define OFF_FSUM  331328    // [NP][B][D]  softmax-weighted feats sum
#define OFF_AGG   478784    // [M][B][D]
#define OFF_E     552512    // [M][B][D]
#define OFF_G     626240    // [M][B][D]
#define OFF_FUSED 699968    // [B][MD]
#define OFF_KL    773696    // [1]

__device__ __forceinline__ float wave_reduce(float v) {
    #pragma unroll
    for (int o = 32; o > 0; o >>= 1) v += __shfl_down(v, o, 64);
    return v;
}

__device__ __forceinline__ float sigmoidf(float x) {
    return 1.0f / (1.0f + __expf(-x));
}

__device__ __forceinline__ float dot4(float4 a, float4 b) {
    return a.x * b.x + a.y * b.y + a.z * b.z + a.w * b.w;
}

// K0a: w_mu[i] = Wq[i]@mu_w[i], etc; w_pk[p] = Wk[j]@pgk_w[i].
// 180 blocks = 15 jobs x 12 row-groups of 64. v held in registers, float4 loads,
// 4 rows in flight per wave (12 independent 1KB loads).
__global__ __launch_bounds__(256) void k_vecs(const float* Wq, const float* Wk,
        const float* mu_w, const float* lv_w, const float* pgq_w, const float* pgk_w,
        float* ws) {
    int blk = blockIdx.x;
    int job = blk / 12, rg = blk % 12;
    const float* Wm; const float* v; float* out;
    if (job < 9) {
        int type = job / 3, i = job % 3;
        Wm = Wq + i * D * D;
        v = (type == 0 ? mu_w : type == 1 ? lv_w : pgq_w) + i * D;
        out = ws + (type == 0 ? OFF_WMU : type == 1 ? OFF_WLV : OFF_WPGQ) + i * D;
    } else {
        int p = job - 9, i = p / 2, c = p % 2, j = c + (c >= i ? 1 : 0);
        Wm = Wk + j * D * D; v = pgk_w + i * D; out = ws + OFF_WPK + p * D;
    }
    int wave = threadIdx.x >> 6, lane = threadIdx.x & 63;
    const float4* v4 = (const float4*)v;
    float4 v0 = v4[lane], v1 = v4[lane + 64], v2 = v4[lane + 128];
    int base = rg * 64 + wave * 16;
    for (int r = 0; r < 16; r += 4) {
        const float4* r0 = (const float4*)(Wm + (base + r + 0) * D);
        const float4* r1 = (const float4*)(Wm + (base + r + 1) * D);
        const float4* r2 = (const float4*)(Wm + (base + r + 2) * D);
        const float4* r3 = (const float4*)(Wm + (base + r + 3) * D);
        float4 a0 = r0[lane], b0 = r0[lane + 64], c0 = r0[lane + 128];
        float4 a1 = r1[lane], b1 = r1[lane + 64], c1 = r1[lane + 128];
        float4 a2 = r2[lane], b2 = r2[lane + 64], c2 = r2[lane + 128];
        float4 a3 = r3[lane], b3 = r3[lane + 64], c3 = r3[lane + 128];
        float s0 = dot4(a0, v0) + dot4(b0, v1) + dot4(c0, v2);
        float s1 = dot4(a1, v0) + dot4(b1, v1) + dot4(c1, v2);
        float s2 = dot4(a2, v0) + dot4(b2, v1) + dot4(c2, v2);
        float s3 = dot4(a3, v0) + dot4(b3, v1) + dot4(c3, v2);
        s0 = wave_reduce(s0); s1 = wave_reduce(s1);
        s2 = wave_reduce(s2); s3 = wave_reduce(s3);
        if (lane == 0) {
            out[base + r + 0] = s0; out[base + r + 1] = s1;
            out[base + r + 2] = s2; out[base + r + 3] = s3;
        }
    }
}

// K0b: scalar constants. 1 block.
__global__ __launch_bounds__(256) void k_scalars(const float* bq, const float* bk,
        const float* mu_w, const float* mu_b, const float* lv_w, const float* lv_b,
        const float* pgq_w, const float* pgq_b, const float* pgk_w, const float* pgk_b,
        float* ws) {
    int wave = threadIdx.x >> 6, lane = threadIdx.x & 63;
    for (int job = wave; job < 15; job += 4) {
        const float* a; const float* bvec; float bias; float* out;
        if (job < 3)      { int i = job;     a = bq + i * D; bvec = mu_w + i * D;  bias = mu_b[i];  out = ws + OFF_CMU + i; }
        else if (job < 6) { int i = job - 3; a = bq + i * D; bvec = lv_w + i * D;  bias = lv_b[i];  out = ws + OFF_CLV + i; }
        else if (job < 9) { int i = job - 6; a = bq + i * D; bvec = pgq_w + i * D; bias = pgq_b[i]; out = ws + OFF_CPGQ + i; }
        else {
            int p = job - 9, i = p / 2, c = p % 2, j = c + (c >= i ? 1 : 0);
            a = bk + j * D; bvec = pgk_w + i * D; bias = pgk_b[i]; out = ws + OFF_CPK + p;
        }
        float acc = 0.f;
        for (int t = lane; t < D; t += 64) acc += a[t] * bvec[t];
        acc = wave_reduce(acc);
        if (lane == 0) *out = acc + bias;
    }
}

// K1: one full pass over feats: mu/lv/pkpre/pqpre + KL. 6144 blocks (4 rows each).
__global__ __launch_bounds__(256) void k_stats(const float* feats, float* ws) {
    __shared__ float klred[4];
    int wave = threadIdx.x >> 6, lane = threadIdx.x & 63;
    int row = blockIdx.x * 4 + wave;          // (m*B+b)*S+s, 0..24575
    int m = row / (B * S);
    int rem = row % (B * S);
    int b = rem / S, s = rem % S;
    const float4* f4 = (const float4*)(feats + row * D);
    float4 x0 = f4[lane], x1 = f4[lane + 64], x2 = f4[lane + 128];
    int plist[2]; int np = 0;
    #pragma unroll
    for (int p = 0; p < NP; p++) {
        int i = p / 2, c = p % 2, j = c + (c >= i ? 1 : 0);
        if (j == m) plist[np++] = p;
    }
    const float4* wmu = (const float4*)(ws + OFF_WMU + m * D);
    const float4* wlv = (const float4*)(ws + OFF_WLV + m * D);
    const float4* wpgq = (const float4*)(ws + OFF_WPGQ + m * D);
    const float4* wpk0 = (const float4*)(ws + OFF_WPK + plist[0] * D);
    const float4* wpk1 = (const float4*)(ws + OFF_WPK + plist[1] * D);
    float amu  = dot4(x0, wmu[lane])  + dot4(x1, wmu[lane + 64])  + dot4(x2, wmu[lane + 128]);
    float alv  = dot4(x0, wlv[lane])  + dot4(x1, wlv[lane + 64])  + dot4(x2, wlv[lane + 128]);
    float apgq = dot4(x0, wpgq[lane]) + dot4(x1, wpgq[lane + 64]) + dot4(x2, wpgq[lane + 128]);
    float apk0 = dot4(x0, wpk0[lane]) + dot4(x1, wpk0[lane + 64]) + dot4(x2, wpk0[lane + 128]);
    float apk1 = dot4(x0, wpk1[lane]) + dot4(x1, wpk1[lane + 64]) + dot4(x2, wpk1[lane + 128]);
    amu = wave_reduce(amu); alv = wave_reduce(alv); apgq = wave_reduce(apgq);
    apk0 = wave_reduce(apk0); apk1 = wave_reduce(apk1);
    if (lane == 0) {
        float muv = amu + ws[OFF_CMU + m];
        float lvv = alv + ws[OFF_CLV + m];
        ws[OFF_MU + row] = muv;
        ws[OFF_LV + row] = lvv;
        ws[OFF_PKPRE + (plist[0] * B + b) * S + s] = apk0 + ws[OFF_CPK + plist[0]];
        ws[OFF_PKPRE + (plist[1] * B + b) * S + s] = apk1 + ws[OFF_CPK + plist[1]];
        if (s == 0) ws[OFF_PQPRE + m * B + b] = apgq + ws[OFF_CPGQ + m];
        float term = 1.0f + lvv - muv * muv - __expf(lvv);
        klred[wave] = term;
    }
    __syncthreads();
    if (threadIdx.x == 0)
        atomicAdd(ws + OFF_KL, -(klred[0] + klred[1] + klred[2] + klred[3]));
}

// K2: q[i,b,:] = feats[i,b,0,:] @ Wq[i] + bq[i].  72 blocks (i, ec 3, bg 8, bb=4).
__global__ __launch_bounds__(256) void k_qrow(const float* feats, const float* Wq,
                                              const float* bq, float* ws) {
    int blk = blockIdx.x;
    int i = blk / 24, r = blk % 24, ec = r / 8, bg = r % 8;
    __shared__ float xs[4][D];
    for (int bb = 0; bb < 4; bb++) {
        const float4* f = (const float4*)(feats + ((i * B + bg * 4 + bb) * S) * D); // s=0
        for (int t = threadIdx.x; t < D / 4; t += 256) ((float4*)xs[bb])[t] = f[t];
    }
    __syncthreads();
    int e = ec * 256 + threadIdx.x;
    const float* Wm = Wq + i * D * D;
    float bias = bq[i * D + e];
    float acc[4];
    #pragma unroll
    for (int bb = 0; bb < 4; bb++) acc[bb] = bias;
    #pragma unroll 4
    for (int d = 0; d < D; d++) {
        float w = Wm[d * D + e];
        #pragma unroll
        for (int bb = 0; bb < 4; bb++) acc[bb] += xs[bb][d] * w;
    }
    #pragma unroll
    for (int bb = 0; bb < 4; bb++) ws[OFF_Q + (i * B + bg * 4 + bb) * D + e] = acc[bb];
}

// K3: qk[p,b,:] = Wk[j] @ q[i,b,:].  96 blocks (p, bg 8 (bb=4), dc 2); q in registers.
__global__ __launch_bounds__(256) void k_qk(const float* Wk, float* ws) {
    int blk = blockIdx.x;
    int p = blk / 16, r = blk % 16, bg = r / 2, dc = r % 2;
    int i = p / 2, c = p % 2, j = c + (c >= i ? 1 : 0);
    int wave = threadIdx.x >> 6, lane = threadIdx.x & 63;
    float4 q0[4], q1[4], q2[4];
    #pragma unroll
    for (int bb = 0; bb < 4; bb++) {
        const float4* q = (const float4*)(ws + OFF_Q + (i * B + bg * 4 + bb) * D);
        q0[bb] = q[lane]; q1[bb] = q[lane + 64]; q2[bb] = q[lane + 128];
    }
    const float* Wm = Wk + j * D * D;
    int dbase = dc * 384 + wave * 96;
    #pragma unroll 2
    for (int dd = 0; dd < 96; dd++) {
        int d = dbase + dd;
        const float4* row = (const float4*)(Wm + d * D);
        float4 wa = row[lane], wb = row[lane + 64], wc = row[lane + 128];
        float a[4];
        #pragma unroll
        for (int bb = 0; bb < 4; bb++)
            a[bb] = dot4(wa, q0[bb]) + dot4(wb, q1[bb]) + dot4(wc, q2[bb]);
        #pragma unroll
        for (int bb = 0; bb < 4; bb++) a[bb] = wave_reduce(a[bb]);
        if (lane == 0) {
            #pragma unroll
            for (int bb = 0; bb < 4; bb++)
                ws[OFF_QK + (p * B + bg * 4 + bb) * D + d] = a[bb];
        }
    }
}

// K3b: qbk[p,b] = q[i,b,:] . bk[j].  6 blocks.
__global__ __launch_bounds__(256) void k_qbk(const float* bk, float* ws) {
    int p = blockIdx.x;
    int i = p / 2, c = p % 2, j = c + (c >= i ? 1 : 0);
    int wave = threadIdx.x >> 6, lane = threadIdx.x & 63;
    const float4* bk4 = (const float4*)(bk + j * D);
    float4 k0 = bk4[lane], k1 = bk4[lane + 64], k2 = bk4[lane + 128];
    for (int b = wave; b < B; b += 4) {
        const float4* q = (const float4*)(ws + OFF_Q + (i * B + b) * D);
        float a = dot4(q[lane], k0) + dot4(q[lane + 64], k1) + dot4(q[lane + 128], k2);
        a = wave_reduce(a);
        if (lane == 0) ws[OFF_QBK + p * B + b] = a;
    }
}

// K4: gated attention row q=0 + softmax + weighted feats sum. 192 blocks (p,b).
__global__ __launch_bounds__(256) void k_attn(const float* feats, const float* eps,
                                              const float* dyn, float* ws) {
    int blk = blockIdx.x;
    int p = blk / B, b = blk % B;
    int i = p / 2, c = p % 2, j = c + (c >= i ? 1 : 0);
    __shared__ float sc[S];
    __shared__ float red[256];
    __shared__ float pqs;
    int wave = threadIdx.x >> 6, lane = threadIdx.x & 63;
    const float4* q4 = (const float4*)(ws + OFF_QK + (p * B + b) * D);
    float4 q0 = q4[lane], q1 = q4[lane + 64], q2 = q4[lane + 128];
    float dynv = dyn[0];
    if (threadIdx.x == 0) {
        float mu0 = ws[OFF_MU + (i * B + b) * S];
        float lv0 = ws[OFF_LV + (i * B + b) * S];
        float e0 = eps[(p * B + b) * S];
        float g0 = sigmoidf(mu0 + dynv * __expf(0.5f * lv0) * e0);
        pqs = sigmoidf(ws[OFF_PQPRE + i * B + b]) * g0;
    }
    float qbk = ws[OFF_QBK + p * B + b];
    const float* fbase = feats + ((j * B + b) * S) * D;
    // score pass: each wave handles 64 contiguous k, 2 at a time
    for (int kk = wave * 64; kk < wave * 64 + 64; kk += 2) {
        const float4* fA = (const float4*)(fbase + kk * D);
        const float4* fB = (const float4*)(fbase + (kk + 1) * D);
        float sA = dot4(fA[lane], q0) + dot4(fA[lane + 64], q1) + dot4(fA[lane + 128], q2);
        float sB = dot4(fB[lane], q0) + dot4(fB[lane + 64], q1) + dot4(fB[lane + 128], q2);
        sA = wave_reduce(sA); sB = wave_reduce(sB);
        if (lane == 0) { sc[kk] = sA; sc[kk + 1] = sB; }
    }
    __syncthreads();
    int t = threadIdx.x;
    {   // gates + pregating, one k per thread
        float muk = ws[OFF_MU + (i * B + b) * S + t];
        float lvk = ws[OFF_LV + (i * B + b) * S + t];
        float ek = eps[(p * B + b) * S + t];
        float g = sigmoidf(muk + dynv * __expf(0.5f * lvk) * ek);
        float pk = sigmoidf(ws[OFF_PKPRE + (p * B + b) * S + t]) * g;
        sc[t] = (sc[t] + qbk) * SCALE * pqs * pk;
    }
    __syncthreads();
    // softmax over 256 scores
    red[t] = sc[t];
    __syncthreads();
    for (int st = 128; st > 0; st >>= 1) {
        if (t < st) red[t] = fmaxf(red[t], red[t + st]);
        __syncthreads();
    }
    float mx = red[0];
    __syncthreads();
    float w = __expf(sc[t] - mx);
    red[t] = w;
    __syncthreads();
    for (int st = 128; st > 0; st >>= 1) {
        if (t < st) red[t] += red[t + st];
        __syncthreads();
    }
    float inv = 1.0f / red[0];
    __syncthreads();
    sc[t] = w * inv;
    __syncthreads();
    // weighted feats sum
    float a0 = 0.f, a1 = 0.f, a2 = 0.f;
    #pragma unroll 2
    for (int k = 0; k < S; k++) {
        float wk = sc[k];
        const float* f = fbase + k * D;
        a0 += wk * f[t]; a1 += wk * f[t + 256]; a2 += wk * f[t + 512];
    }
    float* o = ws + OFF_FSUM + (p * B + b) * D;
    o[t] = a0; o[t + 256] = a1; o[t + 512] = a2;
}

// K5a: agg[i,b,:] = sum_c fsum[p,b,:] @ Wv[j] + bv[j]. 72 blocks (i, ec 3, bg 8, bb=4).
__global__ __launch_bounds__(256) void k_agg(const float* Wv, const float* bv, float* ws) {
    int blk = blockIdx.x;
    int i = blk / 24, r = blk % 24, ec = r / 8, bg = r % 8;
    int j0 = (0 >= i ? 1 : 0);
    int j1 = 1 + (1 >= i ? 1 : 0);
    int p0 = i * 2, p1 = i * 2 + 1;
    __shared__ float f0s[4][D];
    __shared__ float f1s[4][D];
    for (int bb = 0; bb < 4; bb++) {
        const float4* a = (const float4*)(ws + OFF_FSUM + (p0 * B + bg * 4 + bb) * D);
        const float4* b2 = (const float4*)(ws + OFF_FSUM + (p1 * B + bg * 4 + bb) * D);
        for (int t = threadIdx.x; t < D / 4; t += 256) {
            ((float4*)f0s[bb])[t] = a[t]; ((float4*)f1s[bb])[t] = b2[t];
        }
    }
    __syncthreads();
    int e = ec * 256 + threadIdx.x;
    const float* W0 = Wv + j0 * D * D;
    const float* W1 = Wv + j1 * D * D;
    float bias = bv[j0 * D + e] + bv[j1 * D + e];
    float acc[4];
    #pragma unroll
    for (int bb = 0; bb < 4; bb++) acc[bb] = bias;
    #pragma unroll 4
    for (int d = 0; d < D; d++) {
        float w0 = W0[d * D + e], w1 = W1[d * D + e];
        #pragma unroll
        for (int bb = 0; bb < 4; bb++) acc[bb] += f0s[bb][d] * w0 + f1s[bb][d] * w1;
    }
    #pragma unroll
    for (int bb = 0; bb < 4; bb++) ws[OFF_AGG + (i * B + bg * 4 + bb) * D + e] = acc[bb];
}

// K5b: E = relu(agg@WE + WE_b), G = relu(agg@Wh + Wh_b + q@Wqc + Wqc_b). 72 blocks.
__global__ __launch_bounds__(256) void k_eg(const float* WE_w, const float* WE_b,
        const float* Wh_w, const float* Wh_b, const float* Wqc_w, const float* Wqc_b,
        float* ws) {
    int blk = blockIdx.x;
    int i = blk / 24, r = blk % 24, ec = r / 8, bg = r % 8;
    __shared__ float as[4][D];
    __shared__ float qs[4][D];
    for (int bb = 0; bb < 4; bb++) {
        const float4* a = (const float4*)(ws + OFF_AGG + (i * B + bg * 4 + bb) * D);
        const float4* q = (const float4*)(ws + OFF_Q + (i * B + bg * 4 + bb) * D);
        for (int t = threadIdx.x; t < D / 4; t += 256) {
            ((float4*)as[bb])[t] = a[t]; ((float4*)qs[bb])[t] = q[t];
        }
    }
    __syncthreads();
    int e = ec * 256 + threadIdx.x;
    const float* WE = WE_w + i * D * D;
    const float* Wh = Wh_w + i * D * D;
    const float* Wq2 = Wqc_w + i * D * D;
    float eb = WE_b[i * D + e];
    float gb = Wh_b[i * D + e] + Wqc_b[i * D + e];
    float ea[4], ga[4];
    #pragma unroll
    for (int bb = 0; bb < 4; bb++) { ea[bb] = eb; ga[bb] = gb; }
    #pragma unroll 2
    for (int d = 0; d < D; d++) {
        float we = WE[d * D + e], wh = Wh[d * D + e], wq = Wq2[d * D + e];
        #pragma unroll
        for (int bb = 0; bb < 4; bb++) {
            float av = as[bb][d];
            ea[bb] += av * we;
            ga[bb] += av * wh + qs[bb][d] * wq;
        }
    }
    #pragma unroll
    for (int bb = 0; bb < 4; bb++) {
        int idx = (i * B + bg * 4 + bb) * D + e;
        ws[OFF_E + idx] = fmaxf(ea[bb], 0.f);
        ws[OFF_G + idx] = fmaxf(ga[bb], 0.f);
    }
}

// K5c: LayerNorm(E)*LayerNorm(G) -> fused. 96 blocks (i,b).
__global__ __launch_bounds__(256) void k_ln(const float* lnE_g, const float* lnE_b,
        const float* lnG_g, const float* lnG_b, float* ws) {
    int blk = blockIdx.x;
    int i = blk / B, b = blk % B;
    const float* E = ws + OFF_E + (i * B + b) * D;
    const float* G = ws + OFF_G + (i * B + b) * D;
    int t = threadIdx.x;
    float e0 = E[t], e1 = E[t + 256], e2 = E[t + 512];
    float g0 = G[t], g1 = G[t + 256], g2 = G[t + 512];
    __shared__ float r1[256], r2[256], r3[256], r4[256];
    r1[t] = e0 + e1 + e2;
    r2[t] = e0 * e0 + e1 * e1 + e2 * e2;
    r3[t] = g0 + g1 + g2;
    r4[t] = g0 * g0 + g1 * g1 + g2 * g2;
    __syncthreads();
    for (int st = 128; st > 0; st >>= 1) {
        if (t < st) { r1[t] += r1[t + st]; r2[t] += r2[t + st]; r3[t] += r3[t + st]; r4[t] += r4[t + st]; }
        __syncthreads();
    }
    float mE = r1[0] * (1.0f / D), vE = r2[0] * (1.0f / D) - mE * mE;
    float mG = r3[0] * (1.0f / D), vG = r4[0] * (1.0f / D) - mG * mG;
    float sE = rsqrtf(vE + LN_EPS), sG = rsqrtf(vG + LN_EPS);
    float* o = ws + OFF_FUSED + b * MD + i * D;
    const float* eg = lnE_g + i * D; const float* ebv = lnE_b + i * D;
    const float* gg = lnG_g + i * D; const float* gbv = lnG_b + i * D;
    o[t]       = ((e0 - mE) * sE * eg[t]       + ebv[t])       * ((g0 - mG) * sG * gg[t]       + gbv[t]);
    o[t + 256] = ((e1 - mE) * sE * eg[t + 256] + ebv[t + 256]) * ((g1 - mG) * sG * gg[t + 256] + gbv[t + 256]);
    o[t + 512] = ((e2 - mE) * sE * eg[t + 512] + ebv[t + 512]) * ((g2 - mG) * sG * gg[t + 512] + gbv[t + 512]);
}

// K6: out = fused @ out_w + out_b; also writes kl. 64 blocks (hc 4, bg 16, bb=2).
__global__ __launch_bounds__(256) void k_out(const float* out_w, const float* out_b,
                                             float* ws, float* out) {
    int blk = blockIdx.x;
    int hc = blk / 16, bg = blk % 16;
    __shared__ float xs[2][MD];
    for (int bb = 0; bb < 2; bb++) {
        const float4* x = (const float4*)(ws + OFF_FUSED + (bg * 2 + bb) * MD);
        for (int t = threadIdx.x; t < MD / 4; t += 256) ((float4*)xs[bb])[t] = x[t];
    }
    __syncthreads();
    int h = hc * 256 + threadIdx.x;
    float bias = out_b[h];
    float acc[2];
    acc[0] = bias; acc[1] = bias;
    #pragma unroll 4
    for (int f = 0; f < MD; f++) {
        float w = out_w[f * H + h];
        acc[0] += xs[0][f] * w;
        acc[1] += xs[1][f] * w;
    }
    out[(bg * 2 + 0) * H + h] = acc[0];
    out[(bg * 2 + 1) * H + h] = acc[1];
    if (blk == 0 && threadIdx.x == 0) out[B * H] = ws[OFF_KL];
}

extern "C" void kernel_launch(void* const* d_in, const int* in_sizes, int n_in,
                              void* d_out, int out_size, void* d_ws, size_t ws_size,
                              hipStream_t stream) {
    const float* feats = (const float*)d_in[0];
    const float* Wq    = (const float*)d_in[1];
    const float* bq    = (const float*)d_in[2];
    const float* Wk    = (const float*)d_in[3];
    const float* bk    = (const float*)d_in[4];
    const float* Wv    = (const float*)d_in[5];
    const float* bv    = (const float*)d_in[6];
    const float* pgq_w = (const float*)d_in[7];
    const float* pgq_b = (const float*)d_in[8];
    const float* pgk_w = (const float*)d_in[9];
    const float* pgk_b = (const float*)d_in[10];
    const float* mu_w  = (const float*)d_in[11];
    const float* mu_b  = (const float*)d_in[12];
    const float* lv_w  = (const float*)d_in[13];
    const float* lv_b  = (const float*)d_in[14];
    const float* dyn   = (const float*)d_in[15];
    const float* WE_w  = (const float*)d_in[16];
    const float* WE_b  = (const float*)d_in[17];
    const float* Wh_w  = (const float*)d_in[18];
    const float* Wh_b  = (const float*)d_in[19];
    const float* Wqc_w = (const float*)d_in[20];
    const float* Wqc_b = (const float*)d_in[21];
    const float* lnE_g = (const float*)d_in[22];
    const float* lnE_b = (const float*)d_in[23];
    const float* lnG_g = (const float*)d_in[24];
    const float* lnG_b = (const float*)d_in[25];
    const float* out_w = (const float*)d_in[26];
    const float* out_b = (const float*)d_in[27];
    const float* eps   = (const float*)d_in[28];
    float* ws  = (float*)d_ws;
    float* out = (float*)d_out;

    // Zero the KL accumulator (ws is poisoned 0xAA before every timed launch).
    hipMemsetAsync((char*)d_ws + OFF_KL * sizeof(float), 0, sizeof(float), stream);

    k_vecs<<<180, 256, 0, stream>>>(Wq, Wk, mu_w, lv_w, pgq_w, pgk_w, ws);
    k_scalars<<<1, 256, 0, stream>>>(bq, bk, mu_w, mu_b, lv_w, lv_b,
                                     pgq_w, pgq_b, pgk_w, pgk_b, ws);
    k_stats<<<(M * B * S) / 4, 256, 0, stream>>>(feats, ws);
    k_qrow<<<72, 256, 0, stream>>>(feats, Wq, bq, ws);
    k_qk<<<96, 256, 0, stream>>>(Wk, ws);
    k_qbk<<<NP, 256, 0, stream>>>(bk, ws);
    k_attn<<<NP * B, 256, 0, stream>>>(feats, eps, dyn, ws);
    k_agg<<<72, 256, 0, stream>>>(Wv, bv, ws);
    k_eg<<<72, 256, 0, stream>>>(WE_w, WE_b, Wh_w, Wh_b, Wqc_w, Wqc_b, ws);
    k_ln<<<M * B, 256, 0, stream>>>(lnE_g, lnE_b, lnG_g, lnG_b, ws);
    k_out<<<64, 256, 0, stream>>>(out_w, out_b, ws, out);
}

// Round 3
// 536.609 us; speedup vs baseline: 4.4317x; 1.9660x over previous
//
#include <hip/hip_runtime.h>

// Problem constants (fixed by the reference)
#define M 3
#define B 32
#define S 256
#define D 768
#define H 1024
#define MD (M * D)          // 2304
#define NP (M * (M - 1))    // 6 ordered (i,j) pairs, p = i*2 + c, j = c + (c>=i)
#define SCALE 0.03608439182435161f  // 1/sqrt(768)
#define LN_EPS 1e-5f

// Workspace layout (float offsets). Total ~4.32M floats = ~17.3 MB.
#define OFF_WMU   0         // [M][D]   Wq[i] @ mu_w[i]
#define OFF_WLV   2304      // [M][D]   Wq[i] @ lv_w[i]
#define OFF_WPGQ  4608      // [M][D]   Wq[i] @ pgq_w[i]
#define OFF_WPK   6912      // [NP][D]  Wk[j] @ pgk_w[i]
#define OFF_CMU   11520     // [M]
#define OFF_CLV   11523     // [M]
#define OFF_CPGQ  11526     // [M]
#define OFF_CPK   11529     // [NP]
#define OFF_MU    11552     // [M][B][S]
#define OFF_LV    36128     // [M][B][S]
#define OFF_PKPRE 60704     // [NP][B][S]
#define OFF_PQPRE 109856    // [M][B]
#define OFF_Q     109952    // [M][B][D]   q row at s=0 (incl. bq)
#define OFF_QBK   183680    // [NP][B]     q . bk[j]
#define OFF_QK    183872    // [NP][B][D]  Wk[j] @ q
#define OFF_FSUM  331328    // [NP][B][D]  softmax-weighted feats sum
#define OFF_AGG   478784    // [M][B][D]
#define OFF_E     552512    // [M][B][D]
#define OFF_G     626240    // [M][B][D]
#define OFF_FUSED 699968    // [B][MD]
#define OFF_KL    773696    // [1]
#define OFF_WKT   773760    // [M][D][D] Wk transposed (1769472 floats)
#define OFF_ARENA 2543232   // k-split partials, lifetimes sequential (max 1769472 floats)

__device__ __forceinline__ float wave_reduce(float v) {
    #pragma unroll
    for (int o = 32; o > 0; o >>= 1) v += __shfl_down(v, o, 64);
    return v;
}

__device__ __forceinline__ float sigmoidf(float x) {
    return 1.0f / (1.0f + __expf(-x));
}

__device__ __forceinline__ float dot4(float4 a, float4 b) {
    return a.x * b.x + a.y * b.y + a.z * b.z + a.w * b.w;
}

// K0a: all vector-dots per matrix row in one pass. 72 blocks = 6 mats x 12 rowgroups(64).
__global__ __launch_bounds__(256) void k_vecs(const float* Wq, const float* Wk,
        const float* mu_w, const float* lv_w, const float* pgq_w, const float* pgk_w,
        float* ws) {
    int mat = blockIdx.x / 12, rg = blockIdx.x % 12;
    const float* Wm; const float *va, *vb, *vc;
    float *oa, *ob, *oc; int nv;
    if (mat < 3) {
        int i = mat;
        Wm = Wq + i * D * D;
        va = mu_w + i * D; vb = lv_w + i * D; vc = pgq_w + i * D;
        oa = ws + OFF_WMU + i * D; ob = ws + OFF_WLV + i * D; oc = ws + OFF_WPGQ + i * D;
        nv = 3;
    } else {
        int j = mat - 3;
        int i1 = (j == 0) ? 1 : 0, i2 = (j == 2) ? 1 : 2;
        int p1 = 2 * i1 + ((j < i1) ? j : j - 1);
        int p2 = 2 * i2 + ((j < i2) ? j : j - 1);
        Wm = Wk + j * D * D;
        va = pgk_w + i1 * D; vb = pgk_w + i2 * D; vc = va;
        oa = ws + OFF_WPK + p1 * D; ob = ws + OFF_WPK + p2 * D; oc = oa;
        nv = 2;
    }
    int wave = threadIdx.x >> 6, lane = threadIdx.x & 63;
    const float4* va4 = (const float4*)va;
    const float4* vb4 = (const float4*)vb;
    const float4* vc4 = (const float4*)vc;
    float4 A0 = va4[lane], A1 = va4[lane + 64], A2 = va4[lane + 128];
    float4 B0 = vb4[lane], B1 = vb4[lane + 64], B2 = vb4[lane + 128];
    float4 C0 = vc4[lane], C1 = vc4[lane + 64], C2 = vc4[lane + 128];
    int base = rg * 64 + wave * 16;
    #pragma unroll 2
    for (int r = 0; r < 16; r++) {
        const float4* row = (const float4*)(Wm + (base + r) * D);
        float4 x0 = row[lane], x1 = row[lane + 64], x2 = row[lane + 128];
        float da = dot4(x0, A0) + dot4(x1, A1) + dot4(x2, A2);
        float db = dot4(x0, B0) + dot4(x1, B1) + dot4(x2, B2);
        float dc_ = dot4(x0, C0) + dot4(x1, C1) + dot4(x2, C2);
        da = wave_reduce(da); db = wave_reduce(db);
        if (nv == 3) dc_ = wave_reduce(dc_);
        if (lane == 0) {
            oa[base + r] = da; ob[base + r] = db;
            if (nv == 3) oc[base + r] = dc_;
        }
    }
}

// K0b: 15 scalar constants, one block each.
__global__ __launch_bounds__(256) void k_scalars(const float* bq, const float* bk,
        const float* mu_w, const float* mu_b, const float* lv_w, const float* lv_b,
        const float* pgq_w, const float* pgq_b, const float* pgk_w, const float* pgk_b,
        float* ws) {
    int job = blockIdx.x;
    const float *a, *bvec; float bias; float* out;
    if (job < 3)      { int i = job;     a = bq + i * D; bvec = mu_w + i * D;  bias = mu_b[i];  out = ws + OFF_CMU + i; }
    else if (job < 6) { int i = job - 3; a = bq + i * D; bvec = lv_w + i * D;  bias = lv_b[i];  out = ws + OFF_CLV + i; }
    else if (job < 9) { int i = job - 6; a = bq + i * D; bvec = pgq_w + i * D; bias = pgq_b[i]; out = ws + OFF_CPGQ + i; }
    else {
        int p = job - 9, i = p / 2, c = p % 2, j = c + (c >= i ? 1 : 0);
        a = bk + j * D; bvec = pgk_w + i * D; bias = pgk_b[i]; out = ws + OFF_CPK + p;
    }
    int t = threadIdx.x;
    float part = 0.f;
    if (t < 192) part = dot4(((const float4*)a)[t], ((const float4*)bvec)[t]);
    part = wave_reduce(part);
    __shared__ float r[4];
    if ((t & 63) == 0) r[t >> 6] = part;
    __syncthreads();
    if (t == 0) *out = r[0] + r[1] + r[2] + r[3] + bias;
}

// K0c: transpose Wk -> WkT. 432 blocks (j, 12x12 tiles of 64).
__global__ __launch_bounds__(256) void k_trans(const float* Wk, float* ws) {
    int blk = blockIdx.x;
    int j = blk / 144, r = blk % 144;
    int d0 = (r / 12) * 64, e0 = (r % 12) * 64;
    __shared__ float tile[64][65];
    const float* src = Wk + j * D * D;
    for (int idx = threadIdx.x; idx < 4096; idx += 256) {
        int rr = idx / 64, cc = idx % 64;
        tile[rr][cc] = src[(d0 + rr) * D + e0 + cc];
    }
    __syncthreads();
    float* dst = ws + OFF_WKT + j * D * D;
    for (int idx = threadIdx.x; idx < 4096; idx += 256) {
        int rr = idx / 64, cc = idx % 64;
        dst[(e0 + rr) * D + d0 + cc] = tile[cc][rr];
    }
}

// K1: one full pass over feats: mu/lv/pkpre/pqpre + KL. 6144 blocks (4 rows each).
__global__ __launch_bounds__(256) void k_stats(const float* feats, float* ws) {
    __shared__ float klred[4];
    int wave = threadIdx.x >> 6, lane = threadIdx.x & 63;
    int row = blockIdx.x * 4 + wave;
    int m = row / (B * S);
    int rem = row % (B * S);
    int b = rem / S, s = rem % S;
    const float4* f4 = (const float4*)(feats + row * D);
    float4 x0 = f4[lane], x1 = f4[lane + 64], x2 = f4[lane + 128];
    int plist[2]; int np = 0;
    #pragma unroll
    for (int p = 0; p < NP; p++) {
        int i = p / 2, c = p % 2, j = c + (c >= i ? 1 : 0);
        if (j == m) plist[np++] = p;
    }
    const float4* wmu = (const float4*)(ws + OFF_WMU + m * D);
    const float4* wlv = (const float4*)(ws + OFF_WLV + m * D);
    const float4* wpgq = (const float4*)(ws + OFF_WPGQ + m * D);
    const float4* wpk0 = (const float4*)(ws + OFF_WPK + plist[0] * D);
    const float4* wpk1 = (const float4*)(ws + OFF_WPK + plist[1] * D);
    float amu  = dot4(x0, wmu[lane])  + dot4(x1, wmu[lane + 64])  + dot4(x2, wmu[lane + 128]);
    float alv  = dot4(x0, wlv[lane])  + dot4(x1, wlv[lane + 64])  + dot4(x2, wlv[lane + 128]);
    float apgq = dot4(x0, wpgq[lane]) + dot4(x1, wpgq[lane + 64]) + dot4(x2, wpgq[lane + 128]);
    float apk0 = dot4(x0, wpk0[lane]) + dot4(x1, wpk0[lane + 64]) + dot4(x2, wpk0[lane + 128]);
    float apk1 = dot4(x0, wpk1[lane]) + dot4(x1, wpk1[lane + 64]) + dot4(x2, wpk1[lane + 128]);
    amu = wave_reduce(amu); alv = wave_reduce(alv); apgq = wave_reduce(apgq);
    apk0 = wave_reduce(apk0); apk1 = wave_reduce(apk1);
    if (lane == 0) {
        float muv = amu + ws[OFF_CMU + m];
        float lvv = alv + ws[OFF_CLV + m];
        ws[OFF_MU + row] = muv;
        ws[OFF_LV + row] = lvv;
        ws[OFF_PKPRE + (plist[0] * B + b) * S + s] = apk0 + ws[OFF_CPK + plist[0]];
        ws[OFF_PKPRE + (plist[1] * B + b) * S + s] = apk1 + ws[OFF_CPK + plist[1]];
        if (s == 0) ws[OFF_PQPRE + m * B + b] = apgq + ws[OFF_CPGQ + m];
        float term = 1.0f + lvv - muv * muv - __expf(lvv);
        klred[wave] = term;
    }
    __syncthreads();
    if (threadIdx.x == 0)
        atomicAdd(ws + OFF_KL, -(klred[0] + klred[1] + klred[2] + klred[3]));
}

// K2: Pattern A: Q partials. 96 blocks (i 3, bg 2 (16 b), kc 16 (48 k)).
__global__ __launch_bounds__(256) void k_qrow(const float* feats, const float* Wq, float* ws) {
    int blk = blockIdx.x;
    int i = blk / 32, r = blk % 32, bg = r / 16, kc = r % 16;
    int kbase = kc * 48;
    __shared__ __align__(16) float xs[16][48];
    for (int idx = threadIdx.x; idx < 16 * 48; idx += 256) {
        int bb = idx / 48, d = idx % 48;
        xs[bb][d] = feats[((i * B + bg * 16 + bb) * S) * D + kbase + d];
    }
    __syncthreads();
    int e = threadIdx.x;
    const float* Wm = Wq + i * D * D;
    float acc[16][3];
    #pragma unroll
    for (int bb = 0; bb < 16; bb++) { acc[bb][0] = 0.f; acc[bb][1] = 0.f; acc[bb][2] = 0.f; }
    for (int d4 = 0; d4 < 48; d4 += 4) {
        float w[4][3];
        #pragma unroll
        for (int dd = 0; dd < 4; dd++) {
            const float* wr = Wm + (kbase + d4 + dd) * D + e;
            w[dd][0] = wr[0]; w[dd][1] = wr[256]; w[dd][2] = wr[512];
        }
        #pragma unroll
        for (int bb = 0; bb < 16; bb++) {
            float4 x = *(const float4*)&xs[bb][d4];
            acc[bb][0] += x.x * w[0][0] + x.y * w[1][0] + x.z * w[2][0] + x.w * w[3][0];
            acc[bb][1] += x.x * w[0][1] + x.y * w[1][1] + x.z * w[2][1] + x.w * w[3][1];
            acc[bb][2] += x.x * w[0][2] + x.y * w[1][2] + x.z * w[2][2] + x.w * w[3][2];
        }
    }
    #pragma unroll
    for (int bb = 0; bb < 16; bb++) {
        float* pr = ws + OFF_ARENA + kc * 73728 + (i * 32 + bg * 16 + bb) * 768 + e;
        pr[0] = acc[bb][0]; pr[256] = acc[bb][1]; pr[512] = acc[bb][2];
    }
}

// reduce Q partials + bias. 72 blocks.
__global__ __launch_bounds__(256) void k_red_q(const float* bq, float* ws) {
    int idx = blockIdx.x * 256 + threadIdx.x;
    int fidx = idx * 4;
    int i = fidx / 24576, e = fidx % 768;
    float4 a = *(const float4*)&bq[i * 768 + e];
    const float* base = ws + OFF_ARENA;
    #pragma unroll
    for (int kc = 0; kc < 16; kc++) {
        float4 p = *(const float4*)&base[kc * 73728 + fidx];
        a.x += p.x; a.y += p.y; a.z += p.z; a.w += p.w;
    }
    *(float4*)&ws[OFF_Q + fidx] = a;
}

// K3b: qbk[p,b] = q[i,b,:] . bk[j].  6 blocks.
__global__ __launch_bounds__(256) void k_qbk(const float* bk, float* ws) {
    int p = blockIdx.x;
    int i = p / 2, c = p % 2, j = c + (c >= i ? 1 : 0);
    int wave = threadIdx.x >> 6, lane = threadIdx.x & 63;
    const float4* bk4 = (const float4*)(bk + j * D);
    float4 k0 = bk4[lane], k1 = bk4[lane + 64], k2 = bk4[lane + 128];
    for (int b = wave; b < B; b += 4) {
        const float4* q = (const float4*)(ws + OFF_Q + (i * B + b) * D);
        float a = dot4(q[lane], k0) + dot4(q[lane + 64], k1) + dot4(q[lane + 128], k2);
        a = wave_reduce(a);
        if (lane == 0) ws[OFF_QBK + p * B + b] = a;
    }
}

// K3: Pattern A with WkT: qk partials. 96 blocks (j 3, qg 4 (16 qvecs), ec 8 (96 k)).
__global__ __launch_bounds__(256) void k_qk(float* ws) {
    int blk = blockIdx.x;
    int j = blk / 32, r = blk % 32, qg = r / 8, ec = r % 8;
    int kbase = ec * 96;
    int i1 = (j == 0) ? 1 : 0, i2 = (j == 2) ? 1 : 2;
    __shared__ __align__(16) float xs[16][96];
    for (int idx = threadIdx.x; idx < 16 * 96; idx += 256) {
        int v = idx / 96, d = idx % 96;
        int vg = qg * 16 + v;
        int i_ = (vg < 32) ? i1 : i2, b = vg & 31;
        xs[v][d] = ws[OFF_Q + (i_ * 32 + b) * 768 + kbase + d];
    }
    __syncthreads();
    int o = threadIdx.x;
    const float* Wm = ws + OFF_WKT + j * D * D;
    float acc[16][3];
    #pragma unroll
    for (int v = 0; v < 16; v++) { acc[v][0] = 0.f; acc[v][1] = 0.f; acc[v][2] = 0.f; }
    for (int d4 = 0; d4 < 96; d4 += 4) {
        float w[4][3];
        #pragma unroll
        for (int dd = 0; dd < 4; dd++) {
            const float* wr = Wm + (kbase + d4 + dd) * D + o;
            w[dd][0] = wr[0]; w[dd][1] = wr[256]; w[dd][2] = wr[512];
        }
        #pragma unroll
        for (int v = 0; v < 16; v++) {
            float4 x = *(const float4*)&xs[v][d4];
            acc[v][0] += x.x * w[0][0] + x.y * w[1][0] + x.z * w[2][0] + x.w * w[3][0];
            acc[v][1] += x.x * w[0][1] + x.y * w[1][1] + x.z * w[2][1] + x.w * w[3][1];
            acc[v][2] += x.x * w[0][2] + x.y * w[1][2] + x.z * w[2][2] + x.w * w[3][2];
        }
    }
    #pragma unroll
    for (int v = 0; v < 16; v++) {
        float* pr = ws + OFF_ARENA + ((ec * 3 + j) * 64 + qg * 16 + v) * 768 + o;
        pr[0] = acc[v][0]; pr[256] = acc[v][1]; pr[512] = acc[v][2];
    }
}

// reduce qk partials -> QK[p][b][d]. 144 blocks.
__global__ __launch_bounds__(256) void k_red_qk(float* ws) {
    int idx = blockIdx.x * 256 + threadIdx.x;
    int fidx = idx * 4;                      // over 6*32*768
    int p = fidx / 24576, rem = fidx % 24576;
    int b = rem / 768, d = rem % 768;
    int i = p / 2, c = p % 2, j = c + (c >= i ? 1 : 0);
    int i1 = (j == 0) ? 1 : 0;
    int iidx = (i == i1) ? 0 : 1;
    int vg = iidx * 32 + b;
    float4 a = make_float4(0.f, 0.f, 0.f, 0.f);
    #pragma unroll
    for (int ec = 0; ec < 8; ec++) {
        float4 pp = *(const float4*)&ws[OFF_ARENA + ((ec * 3 + j) * 64 + vg) * 768 + d];
        a.x += pp.x; a.y += pp.y; a.z += pp.z; a.w += pp.w;
    }
    *(float4*)&ws[OFF_QK + fidx] = a;
}

// K4: gated attention for BOTH p's sharing (j,b): feats read once. 96 blocks.
__global__ __launch_bounds__(256) void k_attn(const float* feats, const float* eps,
                                              const float* dyn, float* ws) {
    int blk = blockIdx.x;
    int j = blk / B, b = blk % B;
    int i1 = (j == 0) ? 1 : 0, i2 = (j == 2) ? 1 : 2;
    int pA = 2 * i1 + ((j < i1) ? j : j - 1);
    int pB = 2 * i2 + ((j < i2) ? j : j - 1);
    __shared__ float scA[S], scB[S], redm[256];
    int wave = threadIdx.x >> 6, lane = threadIdx.x & 63;
    const float4* qa4 = (const float4*)(ws + OFF_QK + (pA * B + b) * D);
    const float4* qb4 = (const float4*)(ws + OFF_QK + (pB * B + b) * D);
    float4 qA0 = qa4[lane], qA1 = qa4[lane + 64], qA2 = qa4[lane + 128];
    float4 qB0 = qb4[lane], qB1 = qb4[lane + 64], qB2 = qb4[lane + 128];
    float dynv = dyn[0];
    const float* fbase = feats + ((j * B + b) * S) * D;
    for (int k = wave * 64; k < wave * 64 + 64; k += 2) {
        const float4* fA = (const float4*)(fbase + k * D);
        const float4* fB = (const float4*)(fbase + (k + 1) * D);
        float4 xa0 = fA[lane], xa1 = fA[lane + 64], xa2 = fA[lane + 128];
        float4 xb0 = fB[lane], xb1 = fB[lane + 64], xb2 = fB[lane + 128];
        float dA1 = dot4(xa0, qA0) + dot4(xa1, qA1) + dot4(xa2, qA2);
        float dB1 = dot4(xa0, qB0) + dot4(xa1, qB1) + dot4(xa2, qB2);
        float dA2 = dot4(xb0, qA0) + dot4(xb1, qA1) + dot4(xb2, qA2);
        float dB2 = dot4(xb0, qB0) + dot4(xb1, qB1) + dot4(xb2, qB2);
        dA1 = wave_reduce(dA1); dB1 = wave_reduce(dB1);
        dA2 = wave_reduce(dA2); dB2 = wave_reduce(dB2);
        if (lane == 0) { scA[k] = dA1; scB[k] = dB1; scA[k + 1] = dA2; scB[k + 1] = dB2; }
    }
    __syncthreads();
    int t = threadIdx.x;
    {
        // pair A (i1)
        float muk = ws[OFF_MU + (i1 * B + b) * S + t];
        float lvk = ws[OFF_LV + (i1 * B + b) * S + t];
        float ek  = eps[(pA * B + b) * S + t];
        float g   = sigmoidf(muk + dynv * __expf(0.5f * lvk) * ek);
        float pk  = sigmoidf(ws[OFF_PKPRE + (pA * B + b) * S + t]) * g;
        float mu0 = ws[OFF_MU + (i1 * B + b) * S];
        float lv0 = ws[OFF_LV + (i1 * B + b) * S];
        float e0  = eps[(pA * B + b) * S];
        float g0  = sigmoidf(mu0 + dynv * __expf(0.5f * lv0) * e0);
        float pq  = sigmoidf(ws[OFF_PQPRE + i1 * B + b]) * g0;
        float qbk = ws[OFF_QBK + pA * B + b];
        scA[t] = (scA[t] + qbk) * SCALE * pq * pk;
        // pair B (i2)
        muk = ws[OFF_MU + (i2 * B + b) * S + t];
        lvk = ws[OFF_LV + (i2 * B + b) * S + t];
        ek  = eps[(pB * B + b) * S + t];
        g   = sigmoidf(muk + dynv * __expf(0.5f * lvk) * ek);
        pk  = sigmoidf(ws[OFF_PKPRE + (pB * B + b) * S + t]) * g;
        mu0 = ws[OFF_MU + (i2 * B + b) * S];
        lv0 = ws[OFF_LV + (i2 * B + b) * S];
        e0  = eps[(pB * B + b) * S];
        g0  = sigmoidf(mu0 + dynv * __expf(0.5f * lv0) * e0);
        pq  = sigmoidf(ws[OFF_PQPRE + i2 * B + b]) * g0;
        qbk = ws[OFF_QBK + pB * B + b];
        scB[t] = (scB[t] + qbk) * SCALE * pq * pk;
    }
    __syncthreads();
    // softmax A
    redm[t] = scA[t]; __syncthreads();
    for (int st = 128; st > 0; st >>= 1) { if (t < st) redm[t] = fmaxf(redm[t], redm[t + st]); __syncthreads(); }
    float mxA = redm[0]; __syncthreads();
    float wA = __expf(scA[t] - mxA);
    redm[t] = wA; __syncthreads();
    for (int st = 128; st > 0; st >>= 1) { if (t < st) redm[t] += redm[t + st]; __syncthreads(); }
    float sA = redm[0]; __syncthreads();
    scA[t] = wA / sA;
    __syncthreads();
    // softmax B
    redm[t] = scB[t]; __syncthreads();
    for (int st = 128; st > 0; st >>= 1) { if (t < st) redm[t] = fmaxf(redm[t], redm[t + st]); __syncthreads(); }
    float mxB = redm[0]; __syncthreads();
    float wB = __expf(scB[t] - mxB);
    redm[t] = wB; __syncthreads();
    for (int st = 128; st > 0; st >>= 1) { if (t < st) redm[t] += redm[t + st]; __syncthreads(); }
    float sB = redm[0]; __syncthreads();
    scB[t] = wB / sB;
    __syncthreads();
    // weighted feats sums for both p's (second pass hits L2/LLC)
    float aA0 = 0.f, aA1 = 0.f, aA2 = 0.f, aB0 = 0.f, aB1 = 0.f, aB2 = 0.f;
    #pragma unroll 2
    for (int k = 0; k < S; k++) {
        float wa = scA[k], wb = scB[k];
        const float* f = fbase + k * D;
        float f0 = f[t], f1 = f[t + 256], f2 = f[t + 512];
        aA0 += wa * f0; aA1 += wa * f1; aA2 += wa * f2;
        aB0 += wb * f0; aB1 += wb * f1; aB2 += wb * f2;
    }
    float* oA = ws + OFF_FSUM + (pA * B + b) * D;
    float* oB = ws + OFF_FSUM + (pB * B + b) * D;
    oA[t] = aA0; oA[t + 256] = aA1; oA[t + 512] = aA2;
    oB[t] = aB0; oB[t + 256] = aB1; oB[t + 512] = aB2;
}

// K5a: Pattern A: agg partials (2 Wv matmuls fused). 96 blocks (i 3, bg 2, kc 16 (48 k)).
__global__ __launch_bounds__(256) void k_agg(const float* Wv, float* ws) {
    int blk = blockIdx.x;
    int i = blk / 32, r = blk % 32, bg = r / 16, kc = r % 16;
    int kbase = kc * 48;
    int j0 = (i == 0) ? 1 : 0, j1 = (i == 2) ? 1 : 2;
    int p0 = 2 * i, p1 = 2 * i + 1;
    __shared__ __align__(16) float xs0[16][48], xs1[16][48];
    for (int idx = threadIdx.x; idx < 16 * 48; idx += 256) {
        int bb = idx / 48, d = idx % 48;
        xs0[bb][d] = ws[OFF_FSUM + (p0 * B + bg * 16 + bb) * D + kbase + d];
        xs1[bb][d] = ws[OFF_FSUM + (p1 * B + bg * 16 + bb) * D + kbase + d];
    }
    __syncthreads();
    int e = threadIdx.x;
    const float* W0 = Wv + j0 * D * D;
    const float* W1 = Wv + j1 * D * D;
    float acc[16][3];
    #pragma unroll
    for (int bb = 0; bb < 16; bb++) { acc[bb][0] = 0.f; acc[bb][1] = 0.f; acc[bb][2] = 0.f; }
    for (int d4 = 0; d4 < 48; d4 += 4) {
        float w0[4][3], w1[4][3];
        #pragma unroll
        for (int dd = 0; dd < 4; dd++) {
            const float* wr0 = W0 + (kbase + d4 + dd) * D + e;
            const float* wr1 = W1 + (kbase + d4 + dd) * D + e;
            w0[dd][0] = wr0[0]; w0[dd][1] = wr0[256]; w0[dd][2] = wr0[512];
            w1[dd][0] = wr1[0]; w1[dd][1] = wr1[256]; w1[dd][2] = wr1[512];
        }
        #pragma unroll
        for (int bb = 0; bb < 16; bb++) {
            float4 x0 = *(const float4*)&xs0[bb][d4];
            float4 x1 = *(const float4*)&xs1[bb][d4];
            #pragma unroll
            for (int s = 0; s < 3; s++) {
                acc[bb][s] += x0.x * w0[0][s] + x0.y * w0[1][s] + x0.z * w0[2][s] + x0.w * w0[3][s]
                            + x1.x * w1[0][s] + x1.y * w1[1][s] + x1.z * w1[2][s] + x1.w * w1[3][s];
            }
        }
    }
    #pragma unroll
    for (int bb = 0; bb < 16; bb++) {
        float* pr = ws + OFF_ARENA + kc * 73728 + (i * 32 + bg * 16 + bb) * 768 + e;
        pr[0] = acc[bb][0]; pr[256] = acc[bb][1]; pr[512] = acc[bb][2];
    }
}

// reduce agg partials + bv biases. 72 blocks.
__global__ __launch_bounds__(256) void k_red_agg(const float* bv, float* ws) {
    int idx = blockIdx.x * 256 + threadIdx.x;
    int fidx = idx * 4;
    int i = fidx / 24576, e = fidx % 768;
    int j0 = (i == 0) ? 1 : 0, j1 = (i == 2) ? 1 : 2;
    float4 b0 = *(const float4*)&bv[j0 * 768 + e];
    float4 b1 = *(const float4*)&bv[j1 * 768 + e];
    float4 a = make_float4(b0.x + b1.x, b0.y + b1.y, b0.z + b1.z, b0.w + b1.w);
    const float* base = ws + OFF_ARENA;
    #pragma unroll
    for (int kc = 0; kc < 16; kc++) {
        float4 p = *(const float4*)&base[kc * 73728 + fidx];
        a.x += p.x; a.y += p.y; a.z += p.z; a.w += p.w;
    }
    *(float4*)&ws[OFF_AGG + fidx] = a;
}

// K5b: Pattern A: E/G partials (3 matmuls fused). 72 blocks (i 3, bg 2, kc 12 (64 k)).
__global__ __launch_bounds__(256) void k_eg(const float* WE_w, const float* Wh_w,
                                            const float* Wqc_w, float* ws) {
    int blk = blockIdx.x;
    int i = blk / 24, r = blk % 24, bg = r / 12, kc = r % 12;
    int kbase = kc * 64;
    __shared__ __align__(16) float xa[16][64], xq[16][64];
    for (int idx = threadIdx.x; idx < 16 * 64; idx += 256) {
        int bb = idx / 64, d = idx % 64;
        xa[bb][d] = ws[OFF_AGG + (i * B + bg * 16 + bb) * D + kbase + d];
        xq[bb][d] = ws[OFF_Q + (i * B + bg * 16 + bb) * D + kbase + d];
    }
    __syncthreads();
    int e = threadIdx.x;
    const float* WE = WE_w + i * D * D;
    const float* Wh = Wh_w + i * D * D;
    const float* Wc = Wqc_w + i * D * D;
    float accE[16][3], accG[16][3];
    #pragma unroll
    for (int bb = 0; bb < 16; bb++) {
        accE[bb][0] = 0.f; accE[bb][1] = 0.f; accE[bb][2] = 0.f;
        accG[bb][0] = 0.f; accG[bb][1] = 0.f; accG[bb][2] = 0.f;
    }
    for (int d2 = 0; d2 < 64; d2 += 2) {
        float we[2][3], wh[2][3], wc[2][3];
        #pragma unroll
        for (int dd = 0; dd < 2; dd++) {
            const float* r1 = WE + (kbase + d2 + dd) * D + e;
            const float* r2 = Wh + (kbase + d2 + dd) * D + e;
            const float* r3 = Wc + (kbase + d2 + dd) * D + e;
            we[dd][0] = r1[0]; we[dd][1] = r1[256]; we[dd][2] = r1[512];
            wh[dd][0] = r2[0]; wh[dd][1] = r2[256]; wh[dd][2] = r2[512];
            wc[dd][0] = r3[0]; wc[dd][1] = r3[256]; wc[dd][2] = r3[512];
        }
        #pragma unroll
        for (int bb = 0; bb < 16; bb++) {
            float a0 = xa[bb][d2], a1 = xa[bb][d2 + 1];
            float q0 = xq[bb][d2], q1 = xq[bb][d2 + 1];
            #pragma unroll
            for (int s = 0; s < 3; s++) {
                accE[bb][s] += a0 * we[0][s] + a1 * we[1][s];
                accG[bb][s] += a0 * wh[0][s] + a1 * wh[1][s] + q0 * wc[0][s] + q1 * wc[1][s];
            }
        }
    }
    #pragma unroll
    for (int bb = 0; bb < 16; bb++) {
        float* pE = ws + OFF_ARENA + kc * 73728 + (i * 32 + bg * 16 + bb) * 768 + e;
        float* pG = pE + 884736;  // 12*73728
        pE[0] = accE[bb][0]; pE[256] = accE[bb][1]; pE[512] = accE[bb][2];
        pG[0] = accG[bb][0]; pG[256] = accG[bb][1]; pG[512] = accG[bb][2];
    }
}

// reduce E/G partials + bias + relu. 144 blocks (first 72: E, rest: G).
__global__ __launch_bounds__(256) void k_red_eg(const float* WE_b, const float* Wh_b,
                                                const float* Wqc_b, float* ws) {
    int blk = blockIdx.x;
    bool isG = blk >= 72;
    int idx = (isG ? blk - 72 : blk) * 256 + threadIdx.x;
    int fidx = idx * 4;
    int i = fidx / 24576, e = fidx % 768;
    float4 a;
    const float* base = ws + OFF_ARENA + (isG ? 884736 : 0);
    if (isG) {
        float4 b0 = *(const float4*)&Wh_b[i * 768 + e];
        float4 b1 = *(const float4*)&Wqc_b[i * 768 + e];
        a = make_float4(b0.x + b1.x, b0.y + b1.y, b0.z + b1.z, b0.w + b1.w);
    } else {
        a = *(const float4*)&WE_b[i * 768 + e];
    }
    #pragma unroll
    for (int kc = 0; kc < 12; kc++) {
        float4 p = *(const float4*)&base[kc * 73728 + fidx];
        a.x += p.x; a.y += p.y; a.z += p.z; a.w += p.w;
    }
    a.x = fmaxf(a.x, 0.f); a.y = fmaxf(a.y, 0.f); a.z = fmaxf(a.z, 0.f); a.w = fmaxf(a.w, 0.f);
    *(float4*)&ws[(isG ? OFF_G : OFF_E) + fidx] = a;
}

// K5c: LayerNorm(E)*LayerNorm(G) -> fused. 96 blocks (i,b).
__global__ __launch_bounds__(256) void k_ln(const float* lnE_g, const float* lnE_b,
        const float* lnG_g, const float* lnG_b, float* ws) {
    int blk = blockIdx.x;
    int i = blk / B, b = blk % B;
    const float* E = ws + OFF_E + (i * B + b) * D;
    const float* G = ws + OFF_G + (i * B + b) * D;
    int t = threadIdx.x;
    float e0 = E[t], e1 = E[t + 256], e2 = E[t + 512];
    float g0 = G[t], g1 = G[t + 256], g2 = G[t + 512];
    __shared__ float r1[256], r2[256], r3[256], r4[256];
    r1[t] = e0 + e1 + e2;
    r2[t] = e0 * e0 + e1 * e1 + e2 * e2;
    r3[t] = g0 + g1 + g2;
    r4[t] = g0 * g0 + g1 * g1 + g2 * g2;
    __syncthreads();
    for (int st = 128; st > 0; st >>= 1) {
        if (t < st) { r1[t] += r1[t + st]; r2[t] += r2[t + st]; r3[t] += r3[t + st]; r4[t] += r4[t + st]; }
        __syncthreads();
    }
    float mE = r1[0] * (1.0f / D), vE = r2[0] * (1.0f / D) - mE * mE;
    float mG = r3[0] * (1.0f / D), vG = r4[0] * (1.0f / D) - mG * mG;
    float sE = rsqrtf(vE + LN_EPS), sG = rsqrtf(vG + LN_EPS);
    float* o = ws + OFF_FUSED + b * MD + i * D;
    const float* eg = lnE_g + i * D; const float* ebv = lnE_b + i * D;
    const float* gg = lnG_g + i * D; const float* gbv = lnG_b + i * D;
    o[t]       = ((e0 - mE) * sE * eg[t]       + ebv[t])       * ((g0 - mG) * sG * gg[t]       + gbv[t]);
    o[t + 256] = ((e1 - mE) * sE * eg[t + 256] + ebv[t + 256]) * ((g1 - mG) * sG * gg[t + 256] + gbv[t + 256]);
    o[t + 512] = ((e2 - mE) * sE * eg[t + 512] + ebv[t + 512]) * ((g2 - mG) * sG * gg[t + 512] + gbv[t + 512]);
}

// K6: Pattern A: out partials. 48 blocks (bg 2 (16 b), kc 24 (96 f)). Thread owns float4 h.
__global__ __launch_bounds__(256) void k_out(const float* out_w, float* ws) {
    int blk = blockIdx.x;
    int bg = blk / 24, kc = blk % 24;
    int kbase = kc * 96;
    __shared__ __align__(16) float xs[16][96];
    for (int idx = threadIdx.x; idx < 16 * 96; idx += 256) {
        int bb = idx / 96, d = idx % 96;
        xs[bb][d] = ws[OFF_FUSED + (bg * 16 + bb) * MD + kbase + d];
    }
    __syncthreads();
    int h4 = threadIdx.x * 4;
    float4 acc[16];
    #pragma unroll
    for (int bb = 0; bb < 16; bb++) acc[bb] = make_float4(0.f, 0.f, 0.f, 0.f);
    for (int d4 = 0; d4 < 96; d4 += 4) {
        float4 w0 = *(const float4*)&out_w[(kbase + d4 + 0) * H + h4];
        float4 w1 = *(const float4*)&out_w[(kbase + d4 + 1) * H + h4];
        float4 w2 = *(const float4*)&out_w[(kbase + d4 + 2) * H + h4];
        float4 w3 = *(const float4*)&out_w[(kbase + d4 + 3) * H + h4];
        #pragma unroll
        for (int bb = 0; bb < 16; bb++) {
            float4 x = *(const float4*)&xs[bb][d4];
            acc[bb].x += x.x * w0.x + x.y * w1.x + x.z * w2.x + x.w * w3.x;
            acc[bb].y += x.x * w0.y + x.y * w1.y + x.z * w2.y + x.w * w3.y;
            acc[bb].z += x.x * w0.z + x.y * w1.z + x.z * w2.z + x.w * w3.z;
            acc[bb].w += x.x * w0.w + x.y * w1.w + x.z * w2.w + x.w * w3.w;
        }
    }
    #pragma unroll
    for (int bb = 0; bb < 16; bb++)
        *(float4*)&ws[OFF_ARENA + (kc * 32 + bg * 16 + bb) * 1024 + h4] = acc[bb];
}

// final: sum out partials + bias, write kl. 32 blocks (b).
__global__ __launch_bounds__(256) void k_fin(const float* out_b, float* ws, float* out) {
    int b = blockIdx.x;
    int h4 = threadIdx.x * 4;
    float4 a = *(const float4*)&out_b[h4];
    #pragma unroll
    for (int kc = 0; kc < 24; kc++) {
        float4 p = *(const float4*)&ws[OFF_ARENA + (kc * 32 + b) * 1024 + h4];
        a.x += p.x; a.y += p.y; a.z += p.z; a.w += p.w;
    }
    *(float4*)&out[b * H + h4] = a;
    if (b == 0 && threadIdx.x == 0) out[B * H] = ws[OFF_KL];
}

extern "C" void kernel_launch(void* const* d_in, const int* in_sizes, int n_in,
                              void* d_out, int out_size, void* d_ws, size_t ws_size,
                              hipStream_t stream) {
    const float* feats = (const float*)d_in[0];
    const float* Wq    = (const float*)d_in[1];
    const float* bq    = (const float*)d_in[2];
    const float* Wk    = (const float*)d_in[3];
    const float* bk    = (const float*)d_in[4];
    const float* Wv    = (const float*)d_in[5];
    const float* bv    = (const float*)d_in[6];
    const float* pgq_w = (const float*)d_in[7];
    const float* pgq_b = (const float*)d_in[8];
    const float* pgk_w = (const float*)d_in[9];
    const float* pgk_b = (const float*)d_in[10];
    const float* mu_w  = (const float*)d_in[11];
    const float* mu_b  = (const float*)d_in[12];
    const float* lv_w  = (const float*)d_in[13];
    const float* lv_b  = (const float*)d_in[14];
    const float* dyn   = (const float*)d_in[15];
    const float* WE_w  = (const float*)d_in[16];
    const float* WE_b  = (const float*)d_in[17];
    const float* Wh_w  = (const float*)d_in[18];
    const float* Wh_b  = (const float*)d_in[19];
    const float* Wqc_w = (const float*)d_in[20];
    const float* Wqc_b = (const float*)d_in[21];
    const float* lnE_g = (const float*)d_in[22];
    const float* lnE_b = (const float*)d_in[23];
    const float* lnG_g = (const float*)d_in[24];
    const float* lnG_b = (const float*)d_in[25];
    const float* out_w = (const float*)d_in[26];
    const float* out_b = (const float*)d_in[27];
    const float* eps   = (const float*)d_in[28];
    float* ws  = (float*)d_ws;
    float* out = (float*)d_out;

    hipMemsetAsync((char*)d_ws + OFF_KL * sizeof(float), 0, sizeof(float), stream);

    k_vecs<<<72, 256, 0, stream>>>(Wq, Wk, mu_w, lv_w, pgq_w, pgk_w, ws);
    k_scalars<<<15, 256, 0, stream>>>(bq, bk, mu_w, mu_b, lv_w, lv_b,
                                      pgq_w, pgq_b, pgk_w, pgk_b, ws);
    k_trans<<<432, 256, 0, stream>>>(Wk, ws);
    k_stats<<<(M * B * S) / 4, 256, 0, stream>>>(feats, ws);
    k_qrow<<<96, 256, 0, stream>>>(feats, Wq, ws);
    k_red_q<<<72, 256, 0, stream>>>(bq, ws);
    k_qbk<<<NP, 256, 0, stream>>>(bk, ws);
    k_qk<<<96, 256, 0, stream>>>(ws);
    k_red_qk<<<144, 256, 0, stream>>>(ws);
    k_attn<<<M * B, 256, 0, stream>>>(feats, eps, dyn, ws);
    k_agg<<<96, 256, 0, stream>>>(Wv, ws);
    k_red_agg<<<72, 256, 0, stream>>>(bv, ws);
    k_eg<<<72, 256, 0, stream>>>(WE_w, Wh_w, Wqc_w, ws);
    k_red_eg<<<144, 256, 0, stream>>>(WE_b, Wh_b, Wqc_b, ws);
    k_ln<<<M * B, 256, 0, stream>>>(lnE_g, lnE_b, lnG_g, lnG_b, ws);
    k_out<<<48, 256, 0, stream>>>(out_w, ws);
    k_fin<<<32, 256, 0, stream>>>(out_b, ws, out);
}

// Round 4
// 426.732 us; speedup vs baseline: 5.5728x; 1.2575x over previous
//
#include <hip/hip_runtime.h>

// Problem constants (fixed by the reference)
#define M 3
#define B 32
#define S 256
#define D 768
#define H 1024
#define MD (M * D)          // 2304
#define NP (M * (M - 1))    // 6 ordered (i,j) pairs, p = i*2 + c, j = c + (c>=i)
#define SCALE 0.03608439182435161f  // 1/sqrt(768)
#define LN_EPS 1e-5f

// Workspace layout (float offsets). Total ~4.31M floats = ~17.3 MB.
#define OFF_WMU   0         // [M][D]   Wq[i] @ mu_w[i]
#define OFF_WLV   2304      // [M][D]   Wq[i] @ lv_w[i]
#define OFF_WPGQ  4608      // [M][D]   Wq[i] @ pgq_w[i]
#define OFF_WPK   6912      // [NP][D]  Wk[j] @ pgk_w[i]
#define OFF_CMU   11520     // [M]
#define OFF_CLV   11523     // [M]
#define OFF_CPGQ  11526     // [M]
#define OFF_CPK   11529     // [NP]
#define OFF_MU    11552     // [M][B][S]
#define OFF_LV    36128     // [M][B][S]
#define OFF_PKPRE 60704     // [NP][B][S]
#define OFF_PQPRE 109856    // [M][B]
#define OFF_Q     109952    // [M][B][D]   q row at s=0 (incl. bq)
#define OFF_QBK   183680    // [NP][B]     q . bk[j]
#define OFF_QK    183872    // [NP][B][D]  Wk[j] @ q
#define OFF_FSUM  331328    // [NP][B][D]  softmax-weighted feats sum
#define OFF_AGG   478784    // [M][B][D]
#define OFF_E     552512    // [M][B][D]
#define OFF_G     626240    // [M][B][D]
#define OFF_FUSED 699968    // [B][MD]
#define OFF_KL    773696    // [1]
#define OFF_WKT   773760    // [M][D][D] Wk transposed (1769472 floats)
#define OFF_ARENA 2543232   // k-split partials / raw scores; lifetimes sequential

__device__ __forceinline__ float wave_reduce(float v) {
    #pragma unroll
    for (int o = 32; o > 0; o >>= 1) v += __shfl_down(v, o, 64);
    return v;
}

__device__ __forceinline__ float sigmoidf(float x) {
    return 1.0f / (1.0f + __expf(-x));
}

__device__ __forceinline__ float dot4(float4 a, float4 b) {
    return a.x * b.x + a.y * b.y + a.z * b.z + a.w * b.w;
}

// K0: fused prep: blocks 0..71 vector-dots, 72..86 scalar consts, 87..518 Wk transpose.
__global__ __launch_bounds__(256) void k_prep(const float* Wq, const float* Wk,
        const float* bq, const float* bk,
        const float* mu_w, const float* mu_b, const float* lv_w, const float* lv_b,
        const float* pgq_w, const float* pgq_b, const float* pgk_w, const float* pgk_b,
        float* ws) {
    int blk = blockIdx.x;
    if (blk < 72) {
        // ---- vector-dots: 6 mats x 12 rowgroups of 64 ----
        int mat = blk / 12, rg = blk % 12;
        const float* Wm; const float *va, *vb, *vc;
        float *oa, *ob, *oc; int nv;
        if (mat < 3) {
            int i = mat;
            Wm = Wq + i * D * D;
            va = mu_w + i * D; vb = lv_w + i * D; vc = pgq_w + i * D;
            oa = ws + OFF_WMU + i * D; ob = ws + OFF_WLV + i * D; oc = ws + OFF_WPGQ + i * D;
            nv = 3;
        } else {
            int j = mat - 3;
            int i1 = (j == 0) ? 1 : 0, i2 = (j == 2) ? 1 : 2;
            int p1 = 2 * i1 + ((j < i1) ? j : j - 1);
            int p2 = 2 * i2 + ((j < i2) ? j : j - 1);
            Wm = Wk + j * D * D;
            va = pgk_w + i1 * D; vb = pgk_w + i2 * D; vc = va;
            oa = ws + OFF_WPK + p1 * D; ob = ws + OFF_WPK + p2 * D; oc = oa;
            nv = 2;
        }
        int wave = threadIdx.x >> 6, lane = threadIdx.x & 63;
        const float4* va4 = (const float4*)va;
        const float4* vb4 = (const float4*)vb;
        const float4* vc4 = (const float4*)vc;
        float4 A0 = va4[lane], A1 = va4[lane + 64], A2 = va4[lane + 128];
        float4 B0 = vb4[lane], B1 = vb4[lane + 64], B2 = vb4[lane + 128];
        float4 C0 = vc4[lane], C1 = vc4[lane + 64], C2 = vc4[lane + 128];
        int base = rg * 64 + wave * 16;
        for (int r = 0; r < 16; r += 2) {
            const float4* rowP = (const float4*)(Wm + (base + r) * D);
            const float4* rowQ = (const float4*)(Wm + (base + r + 1) * D);
            float4 x0 = rowP[lane], x1 = rowP[lane + 64], x2 = rowP[lane + 128];
            float4 y0 = rowQ[lane], y1 = rowQ[lane + 64], y2 = rowQ[lane + 128];
            float daP = dot4(x0, A0) + dot4(x1, A1) + dot4(x2, A2);
            float dbP = dot4(x0, B0) + dot4(x1, B1) + dot4(x2, B2);
            float dcP = dot4(x0, C0) + dot4(x1, C1) + dot4(x2, C2);
            float daQ = dot4(y0, A0) + dot4(y1, A1) + dot4(y2, A2);
            float dbQ = dot4(y0, B0) + dot4(y1, B1) + dot4(y2, B2);
            float dcQ = dot4(y0, C0) + dot4(y1, C1) + dot4(y2, C2);
            daP = wave_reduce(daP); dbP = wave_reduce(dbP);
            daQ = wave_reduce(daQ); dbQ = wave_reduce(dbQ);
            if (nv == 3) { dcP = wave_reduce(dcP); dcQ = wave_reduce(dcQ); }
            if (lane == 0) {
                oa[base + r] = daP; ob[base + r] = dbP;
                oa[base + r + 1] = daQ; ob[base + r + 1] = dbQ;
                if (nv == 3) { oc[base + r] = dcP; oc[base + r + 1] = dcQ; }
            }
        }
    } else if (blk < 87) {
        // ---- 15 scalar constants ----
        int job = blk - 72;
        const float *a, *bvec; float bias; float* out;
        if (job < 3)      { int i = job;     a = bq + i * D; bvec = mu_w + i * D;  bias = mu_b[i];  out = ws + OFF_CMU + i; }
        else if (job < 6) { int i = job - 3; a = bq + i * D; bvec = lv_w + i * D;  bias = lv_b[i];  out = ws + OFF_CLV + i; }
        else if (job < 9) { int i = job - 6; a = bq + i * D; bvec = pgq_w + i * D; bias = pgq_b[i]; out = ws + OFF_CPGQ + i; }
        else {
            int p = job - 9, i = p / 2, c = p % 2, j = c + (c >= i ? 1 : 0);
            a = bk + j * D; bvec = pgk_w + i * D; bias = pgk_b[i]; out = ws + OFF_CPK + p;
        }
        int t = threadIdx.x;
        float part = 0.f;
        if (t < 192) part = dot4(((const float4*)a)[t], ((const float4*)bvec)[t]);
        part = wave_reduce(part);
        __shared__ float r[4];
        if ((t & 63) == 0) r[t >> 6] = part;
        __syncthreads();
        if (t == 0) *out = r[0] + r[1] + r[2] + r[3] + bias;
    } else {
        // ---- transpose Wk -> WkT: 432 blocks (j, 12x12 tiles of 64) ----
        int r = blk - 87;
        int j = r / 144; r = r % 144;
        int d0 = (r / 12) * 64, e0 = (r % 12) * 64;
        __shared__ float tile[64][65];
        const float* src = Wk + j * D * D;
        for (int idx = threadIdx.x; idx < 4096; idx += 256) {
            int rr = idx / 64, cc = idx % 64;
            tile[rr][cc] = src[(d0 + rr) * D + e0 + cc];
        }
        __syncthreads();
        float* dst = ws + OFF_WKT + j * D * D;
        for (int idx = threadIdx.x; idx < 4096; idx += 256) {
            int rr = idx / 64, cc = idx % 64;
            dst[(e0 + rr) * D + d0 + cc] = tile[cc][rr];
        }
    }
}

// K1: full feats pass: mu/lv/pkpre/pqpre + KL. 1536 blocks; wave owns 4 rows (ILP).
__global__ __launch_bounds__(256) void k_stats(const float* feats, float* ws) {
    __shared__ float klred[4];
    int wave = threadIdx.x >> 6, lane = threadIdx.x & 63;
    int m = blockIdx.x / 512;                       // 512 blocks per modality
    int row0 = blockIdx.x * 16 + wave * 4;          // 4 consecutive rows
    int i1 = (m == 0) ? 1 : 0, i2 = (m == 2) ? 1 : 2;
    int p0 = 2 * i1 + ((m < i1) ? m : m - 1);
    int p1 = 2 * i2 + ((m < i2) ? m : m - 1);
    const float4* wmu  = (const float4*)(ws + OFF_WMU + m * D);
    const float4* wlv  = (const float4*)(ws + OFF_WLV + m * D);
    const float4* wpgq = (const float4*)(ws + OFF_WPGQ + m * D);
    const float4* wpk0 = (const float4*)(ws + OFF_WPK + p0 * D);
    const float4* wpk1 = (const float4*)(ws + OFF_WPK + p1 * D);
    float4 U0 = wmu[lane],  U1 = wmu[lane + 64],  U2 = wmu[lane + 128];
    float4 L0 = wlv[lane],  L1 = wlv[lane + 64],  L2 = wlv[lane + 128];
    float4 Q0 = wpgq[lane], Q1 = wpgq[lane + 64], Q2 = wpgq[lane + 128];
    float4 P0 = wpk0[lane], P1 = wpk0[lane + 64], P2 = wpk0[lane + 128];
    float4 R0 = wpk1[lane], R1 = wpk1[lane + 64], R2 = wpk1[lane + 128];
    float4 x[4][3];
    #pragma unroll
    for (int rr = 0; rr < 4; rr++) {
        const float4* f = (const float4*)(feats + (size_t)(row0 + rr) * D);
        x[rr][0] = f[lane]; x[rr][1] = f[lane + 64]; x[rr][2] = f[lane + 128];
    }
    float amu[4], alv[4], apgq[4], apk0[4], apk1[4];
    #pragma unroll
    for (int rr = 0; rr < 4; rr++) {
        amu[rr]  = dot4(x[rr][0], U0) + dot4(x[rr][1], U1) + dot4(x[rr][2], U2);
        alv[rr]  = dot4(x[rr][0], L0) + dot4(x[rr][1], L1) + dot4(x[rr][2], L2);
        apgq[rr] = dot4(x[rr][0], Q0) + dot4(x[rr][1], Q1) + dot4(x[rr][2], Q2);
        apk0[rr] = dot4(x[rr][0], P0) + dot4(x[rr][1], P1) + dot4(x[rr][2], P2);
        apk1[rr] = dot4(x[rr][0], R0) + dot4(x[rr][1], R1) + dot4(x[rr][2], R2);
    }
    #pragma unroll
    for (int rr = 0; rr < 4; rr++) {
        amu[rr] = wave_reduce(amu[rr]);  alv[rr] = wave_reduce(alv[rr]);
        apgq[rr] = wave_reduce(apgq[rr]);
        apk0[rr] = wave_reduce(apk0[rr]); apk1[rr] = wave_reduce(apk1[rr]);
    }
    if (lane == 0) {
        float cmu = ws[OFF_CMU + m], clv = ws[OFF_CLV + m];
        float cpgq = ws[OFF_CPGQ + m];
        float cpk0 = ws[OFF_CPK + p0], cpk1 = ws[OFF_CPK + p1];
        float klsum = 0.f;
        #pragma unroll
        for (int rr = 0; rr < 4; rr++) {
            int row = row0 + rr;
            int rem = row % (B * S);
            int b = rem / S, s = rem % S;
            float muv = amu[rr] + cmu;
            float lvv = alv[rr] + clv;
            ws[OFF_MU + row] = muv;
            ws[OFF_LV + row] = lvv;
            ws[OFF_PKPRE + (p0 * B + b) * S + s] = apk0[rr] + cpk0;
            ws[OFF_PKPRE + (p1 * B + b) * S + s] = apk1[rr] + cpk1;
            if (s == 0) ws[OFF_PQPRE + m * B + b] = apgq[rr] + cpgq;
            klsum += 1.0f + lvv - muv * muv - __expf(lvv);
        }
        klred[wave] = klsum;
    }
    __syncthreads();
    if (threadIdx.x == 0)
        atomicAdd(ws + OFF_KL, -(klred[0] + klred[1] + klred[2] + klred[3]));
}

// K2: Pattern A: Q partials. 96 blocks (i 3, bg 2 (16 b), kc 16 (48 k)).
__global__ __launch_bounds__(256) void k_qrow(const float* feats, const float* Wq, float* ws) {
    int blk = blockIdx.x;
    int i = blk / 32, r = blk % 32, bg = r / 16, kc = r % 16;
    int kbase = kc * 48;
    __shared__ __align__(16) float xs[16][48];
    for (int idx = threadIdx.x; idx < 16 * 48; idx += 256) {
        int bb = idx / 48, d = idx % 48;
        xs[bb][d] = feats[((i * B + bg * 16 + bb) * S) * D + kbase + d];
    }
    __syncthreads();
    int e = threadIdx.x;
    const float* Wm = Wq + i * D * D;
    float acc[16][3];
    #pragma unroll
    for (int bb = 0; bb < 16; bb++) { acc[bb][0] = 0.f; acc[bb][1] = 0.f; acc[bb][2] = 0.f; }
    for (int d4 = 0; d4 < 48; d4 += 4) {
        float w[4][3];
        #pragma unroll
        for (int dd = 0; dd < 4; dd++) {
            const float* wr = Wm + (kbase + d4 + dd) * D + e;
            w[dd][0] = wr[0]; w[dd][1] = wr[256]; w[dd][2] = wr[512];
        }
        #pragma unroll
        for (int bb = 0; bb < 16; bb++) {
            float4 x = *(const float4*)&xs[bb][d4];
            acc[bb][0] += x.x * w[0][0] + x.y * w[1][0] + x.z * w[2][0] + x.w * w[3][0];
            acc[bb][1] += x.x * w[0][1] + x.y * w[1][1] + x.z * w[2][1] + x.w * w[3][1];
            acc[bb][2] += x.x * w[0][2] + x.y * w[1][2] + x.z * w[2][2] + x.w * w[3][2];
        }
    }
    #pragma unroll
    for (int bb = 0; bb < 16; bb++) {
        float* pr = ws + OFF_ARENA + kc * 73728 + (i * 32 + bg * 16 + bb) * 768 + e;
        pr[0] = acc[bb][0]; pr[256] = acc[bb][1]; pr[512] = acc[bb][2];
    }
}

// reduce Q partials + bias; also qbk for both pairs. 96 blocks (i,b).
__global__ __launch_bounds__(256) void k_red_q(const float* bq, const float* bk, float* ws) {
    int blk = blockIdx.x;
    int i = blk / B, b = blk % B;
    int fbase = (i * B + b) * D;
    int t = threadIdx.x;
    __shared__ float4 qsh[192];
    __shared__ float redsh[8];
    if (t < 192) {
        float4 a = *(const float4*)&bq[i * D + t * 4];
        #pragma unroll
        for (int kc = 0; kc < 16; kc++) {
            float4 v = *(const float4*)&ws[OFF_ARENA + kc * 73728 + fbase + t * 4];
            a.x += v.x; a.y += v.y; a.z += v.z; a.w += v.w;
        }
        *(float4*)&ws[OFF_Q + fbase + t * 4] = a;
        qsh[t] = a;
    }
    __syncthreads();
    int jA = (i == 0) ? 1 : 0, jB = (i == 2) ? 1 : 2;
    float pA_ = 0.f, pB_ = 0.f;
    if (t < 192) {
        float4 q = qsh[t];
        pA_ = dot4(q, *(const float4*)&bk[jA * D + t * 4]);
        pB_ = dot4(q, *(const float4*)&bk[jB * D + t * 4]);
    }
    pA_ = wave_reduce(pA_); pB_ = wave_reduce(pB_);
    int wave = t >> 6, lane = t & 63;
    if (lane == 0) { redsh[wave] = pA_; redsh[4 + wave] = pB_; }
    __syncthreads();
    if (t == 0) {
        ws[OFF_QBK + (2 * i) * B + b]     = redsh[0] + redsh[1] + redsh[2] + redsh[3];
        ws[OFF_QBK + (2 * i + 1) * B + b] = redsh[4] + redsh[5] + redsh[6] + redsh[7];
    }
}

// K3: Pattern A with WkT: qk partials. 96 blocks (j 3, qg 4 (16 qvecs), ec 8 (96 k)).
__global__ __launch_bounds__(256) void k_qk(float* ws) {
    int blk = blockIdx.x;
    int j = blk / 32, r = blk % 32, qg = r / 8, ec = r % 8;
    int kbase = ec * 96;
    int i1 = (j == 0) ? 1 : 0, i2 = (j == 2) ? 1 : 2;
    __shared__ __align__(16) float xs[16][96];
    for (int idx = threadIdx.x; idx < 16 * 96; idx += 256) {
        int v = idx / 96, d = idx % 96;
        int vg = qg * 16 + v;
        int i_ = (vg < 32) ? i1 : i2, b = vg & 31;
        xs[v][d] = ws[OFF_Q + (i_ * 32 + b) * 768 + kbase + d];
    }
    __syncthreads();
    int o = threadIdx.x;
    const float* Wm = ws + OFF_WKT + j * D * D;
    float acc[16][3];
    #pragma unroll
    for (int v = 0; v < 16; v++) { acc[v][0] = 0.f; acc[v][1] = 0.f; acc[v][2] = 0.f; }
    for (int d4 = 0; d4 < 96; d4 += 4) {
        float w[4][3];
        #pragma unroll
        for (int dd = 0; dd < 4; dd++) {
            const float* wr = Wm + (kbase + d4 + dd) * D + o;
            w[dd][0] = wr[0]; w[dd][1] = wr[256]; w[dd][2] = wr[512];
        }
        #pragma unroll
        for (int v = 0; v < 16; v++) {
            float4 x = *(const float4*)&xs[v][d4];
            acc[v][0] += x.x * w[0][0] + x.y * w[1][0] + x.z * w[2][0] + x.w * w[3][0];
            acc[v][1] += x.x * w[0][1] + x.y * w[1][1] + x.z * w[2][1] + x.w * w[3][1];
            acc[v][2] += x.x * w[0][2] + x.y * w[1][2] + x.z * w[2][2] + x.w * w[3][2];
        }
    }
    #pragma unroll
    for (int v = 0; v < 16; v++) {
        float* pr = ws + OFF_ARENA + ((ec * 3 + j) * 64 + qg * 16 + v) * 768 + o;
        pr[0] = acc[v][0]; pr[256] = acc[v][1]; pr[512] = acc[v][2];
    }
}

// reduce qk partials -> QK[p][b][d]. 144 blocks.
__global__ __launch_bounds__(256) void k_red_qk(float* ws) {
    int idx = blockIdx.x * 256 + threadIdx.x;
    int fidx = idx * 4;                      // over 6*32*768
    int p = fidx / 24576, rem = fidx % 24576;
    int b = rem / 768, d = rem % 768;
    int i = p / 2, c = p % 2, j = c + (c >= i ? 1 : 0);
    int i1 = (j == 0) ? 1 : 0;
    int iidx = (i == i1) ? 0 : 1;
    int vg = iidx * 32 + b;
    float4 a = make_float4(0.f, 0.f, 0.f, 0.f);
    #pragma unroll
    for (int ec = 0; ec < 8; ec++) {
        float4 pp = *(const float4*)&ws[OFF_ARENA + ((ec * 3 + j) * 64 + vg) * 768 + d];
        a.x += pp.x; a.y += pp.y; a.z += pp.z; a.w += pp.w;
    }
    *(float4*)&ws[OFF_QK + fidx] = a;
}

// K4a: raw attention dots for both p's sharing (j,b). 384 blocks (j, b, kc 4).
// Writes scores to arena: [ (j*B+b)*2*S ] A then B.
__global__ __launch_bounds__(256) void k_score(const float* feats, float* ws) {
    int blk = blockIdx.x;
    int j = blk / 128, r = blk % 128, b = r / 4, kc = r % 4;
    int i1 = (j == 0) ? 1 : 0, i2 = (j == 2) ? 1 : 2;
    int pA = 2 * i1 + ((j < i1) ? j : j - 1);
    int pB = 2 * i2 + ((j < i2) ? j : j - 1);
    int wave = threadIdx.x >> 6, lane = threadIdx.x & 63;
    const float4* qa4 = (const float4*)(ws + OFF_QK + (pA * B + b) * D);
    const float4* qb4 = (const float4*)(ws + OFF_QK + (pB * B + b) * D);
    float4 qA0 = qa4[lane], qA1 = qa4[lane + 64], qA2 = qa4[lane + 128];
    float4 qB0 = qb4[lane], qB1 = qb4[lane + 64], qB2 = qb4[lane + 128];
    const float* fbase = feats + ((j * B + b) * S) * D;
    float* scA = ws + OFF_ARENA + ((j * B + b) * 2) * S;
    float* scB = scA + S;
    int k0 = kc * 64 + wave * 16;
    for (int k = k0; k < k0 + 16; k += 4) {
        float4 x[4][3];
        #pragma unroll
        for (int rr = 0; rr < 4; rr++) {
            const float4* f = (const float4*)(fbase + (k + rr) * D);
            x[rr][0] = f[lane]; x[rr][1] = f[lane + 64]; x[rr][2] = f[lane + 128];
        }
        float dA[4], dB[4];
        #pragma unroll
        for (int rr = 0; rr < 4; rr++) {
            dA[rr] = dot4(x[rr][0], qA0) + dot4(x[rr][1], qA1) + dot4(x[rr][2], qA2);
            dB[rr] = dot4(x[rr][0], qB0) + dot4(x[rr][1], qB1) + dot4(x[rr][2], qB2);
        }
        #pragma unroll
        for (int rr = 0; rr < 4; rr++) { dA[rr] = wave_reduce(dA[rr]); dB[rr] = wave_reduce(dB[rr]); }
        if (lane == 0) {
            #pragma unroll
            for (int rr = 0; rr < 4; rr++) { scA[k + rr] = dA[rr]; scB[k + rr] = dB[rr]; }
        }
    }
}

// K4b: gates + softmax + weighted feats sum stripe. 288 blocks (j, b, dc 3).
__global__ __launch_bounds__(256) void k_wsum(const float* feats, const float* eps,
                                              const float* dyn, float* ws) {
    int blk = blockIdx.x;
    int j = blk / 96, r = blk % 96, b = r / 3, dc = r % 3;
    int i1 = (j == 0) ? 1 : 0, i2 = (j == 2) ? 1 : 2;
    int pA = 2 * i1 + ((j < i1) ? j : j - 1);
    int pB = 2 * i2 + ((j < i2) ? j : j - 1);
    __shared__ float sA[S], sB[S], redm[256];
    int t = threadIdx.x;
    float dynv = dyn[0];
    const float* rawA = ws + OFF_ARENA + ((j * B + b) * 2) * S;
    const float* rawB = rawA + S;
    {
        // pair A (i1)
        float muk = ws[OFF_MU + (i1 * B + b) * S + t];
        float lvk = ws[OFF_LV + (i1 * B + b) * S + t];
        float ek  = eps[(pA * B + b) * S + t];
        float g   = sigmoidf(muk + dynv * __expf(0.5f * lvk) * ek);
        float pk  = sigmoidf(ws[OFF_PKPRE + (pA * B + b) * S + t]) * g;
        float mu0 = ws[OFF_MU + (i1 * B + b) * S];
        float lv0 = ws[OFF_LV + (i1 * B + b) * S];
        float e0  = eps[(pA * B + b) * S];
        float g0  = sigmoidf(mu0 + dynv * __expf(0.5f * lv0) * e0);
        float pq  = sigmoidf(ws[OFF_PQPRE + i1 * B + b]) * g0;
        float qbk = ws[OFF_QBK + pA * B + b];
        sA[t] = (rawA[t] + qbk) * SCALE * pq * pk;
        // pair B (i2)
        muk = ws[OFF_MU + (i2 * B + b) * S + t];
        lvk = ws[OFF_LV + (i2 * B + b) * S + t];
        ek  = eps[(pB * B + b) * S + t];
        g   = sigmoidf(muk + dynv * __expf(0.5f * lvk) * ek);
        pk  = sigmoidf(ws[OFF_PKPRE + (pB * B + b) * S + t]) * g;
        mu0 = ws[OFF_MU + (i2 * B + b) * S];
        lv0 = ws[OFF_LV + (i2 * B + b) * S];
        e0  = eps[(pB * B + b) * S];
        g0  = sigmoidf(mu0 + dynv * __expf(0.5f * lv0) * e0);
        pq  = sigmoidf(ws[OFF_PQPRE + i2 * B + b]) * g0;
        qbk = ws[OFF_QBK + pB * B + b];
        sB[t] = (rawB[t] + qbk) * SCALE * pq * pk;
    }
    __syncthreads();
    // softmax A
    redm[t] = sA[t]; __syncthreads();
    for (int st = 128; st > 0; st >>= 1) { if (t < st) redm[t] = fmaxf(redm[t], redm[t + st]); __syncthreads(); }
    float mxA = redm[0]; __syncthreads();
    float wA = __expf(sA[t] - mxA);
    redm[t] = wA; __syncthreads();
    for (int st = 128; st > 0; st >>= 1) { if (t < st) redm[t] += redm[t + st]; __syncthreads(); }
    float sumA = redm[0]; __syncthreads();
    sA[t] = wA / sumA;
    __syncthreads();
    // softmax B
    redm[t] = sB[t]; __syncthreads();
    for (int st = 128; st > 0; st >>= 1) { if (t < st) redm[t] = fmaxf(redm[t], redm[t + st]); __syncthreads(); }
    float mxB = redm[0]; __syncthreads();
    float wB = __expf(sB[t] - mxB);
    redm[t] = wB; __syncthreads();
    for (int st = 128; st > 0; st >>= 1) { if (t < st) redm[t] += redm[t + st]; __syncthreads(); }
    float sumB = redm[0]; __syncthreads();
    sB[t] = wB / sumB;
    __syncthreads();
    // weighted sum over this 256-dim stripe
    int dim = dc * 256 + t;
    const float* fcol = feats + ((j * B + b) * S) * D + dim;
    float accA = 0.f, accB = 0.f;
    #pragma unroll 8
    for (int k = 0; k < S; k++) {
        float fv = fcol[k * D];
        accA += sA[k] * fv;
        accB += sB[k] * fv;
    }
    ws[OFF_FSUM + (pA * B + b) * D + dim] = accA;
    ws[OFF_FSUM + (pB * B + b) * D + dim] = accB;
}

// K5a: Pattern A: agg partials (2 Wv matmuls fused). 96 blocks (i 3, bg 2, kc 16 (48 k)).
__global__ __launch_bounds__(256) void k_agg(const float* Wv, float* ws) {
    int blk = blockIdx.x;
    int i = blk / 32, r = blk % 32, bg = r / 16, kc = r % 16;
    int kbase = kc * 48;
    int j0 = (i == 0) ? 1 : 0, j1 = (i == 2) ? 1 : 2;
    int p0 = 2 * i, p1 = 2 * i + 1;
    __shared__ __align__(16) float xs0[16][48], xs1[16][48];
    for (int idx = threadIdx.x; idx < 16 * 48; idx += 256) {
        int bb = idx / 48, d = idx % 48;
        xs0[bb][d] = ws[OFF_FSUM + (p0 * B + bg * 16 + bb) * D + kbase + d];
        xs1[bb][d] = ws[OFF_FSUM + (p1 * B + bg * 16 + bb) * D + kbase + d];
    }
    __syncthreads();
    int e = threadIdx.x;
    const float* W0 = Wv + j0 * D * D;
    const float* W1 = Wv + j1 * D * D;
    float acc[16][3];
    #pragma unroll
    for (int bb = 0; bb < 16; bb++) { acc[bb][0] = 0.f; acc[bb][1] = 0.f; acc[bb][2] = 0.f; }
    for (int d4 = 0; d4 < 48; d4 += 4) {
        float w0[4][3], w1[4][3];
        #pragma unroll
        for (int dd = 0; dd < 4; dd++) {
            const float* wr0 = W0 + (kbase + d4 + dd) * D + e;
            const float* wr1 = W1 + (kbase + d4 + dd) * D + e;
            w0[dd][0] = wr0[0]; w0[dd][1] = wr0[256]; w0[dd][2] = wr0[512];
            w1[dd][0] = wr1[0]; w1[dd][1] = wr1[256]; w1[dd][2] = wr1[512];
        }
        #pragma unroll
        for (int bb = 0; bb < 16; bb++) {
            float4 x0 = *(const float4*)&xs0[bb][d4];
            float4 x1 = *(const float4*)&xs1[bb][d4];
            #pragma unroll
            for (int s = 0; s < 3; s++) {
                acc[bb][s] += x0.x * w0[0][s] + x0.y * w0[1][s] + x0.z * w0[2][s] + x0.w * w0[3][s]
                            + x1.x * w1[0][s] + x1.y * w1[1][s] + x1.z * w1[2][s] + x1.w * w1[3][s];
            }
        }
    }
    #pragma unroll
    for (int bb = 0; bb < 16; bb++) {
        float* pr = ws + OFF_ARENA + kc * 73728 + (i * 32 + bg * 16 + bb) * 768 + e;
        pr[0] = acc[bb][0]; pr[256] = acc[bb][1]; pr[512] = acc[bb][2];
    }
}

// reduce agg partials + bv biases. 72 blocks.
__global__ __launch_bounds__(256) void k_red_agg(const float* bv, float* ws) {
    int idx = blockIdx.x * 256 + threadIdx.x;
    int fidx = idx * 4;
    int i = fidx / 24576, e = fidx % 768;
    int j0 = (i == 0) ? 1 : 0, j1 = (i == 2) ? 1 : 2;
    float4 b0 = *(const float4*)&bv[j0 * 768 + e];
    float4 b1 = *(const float4*)&bv[j1 * 768 + e];
    float4 a = make_float4(b0.x + b1.x, b0.y + b1.y, b0.z + b1.z, b0.w + b1.w);
    const float* base = ws + OFF_ARENA;
    #pragma unroll
    for (int kc = 0; kc < 16; kc++) {
        float4 p = *(const float4*)&base[kc * 73728 + fidx];
        a.x += p.x; a.y += p.y; a.z += p.z; a.w += p.w;
    }
    *(float4*)&ws[OFF_AGG + fidx] = a;
}

// K5b: Pattern A: E/G partials (3 matmuls fused). 72 blocks (i 3, bg 2, kc 12 (64 k)).
__global__ __launch_bounds__(256) void k_eg(const float* WE_w, const float* Wh_w,
                                            const float* Wqc_w, float* ws) {
    int blk = blockIdx.x;
    int i = blk / 24, r = blk % 24, bg = r / 12, kc = r % 12;
    int kbase = kc * 64;
    __shared__ __align__(16) float xa[16][64], xq[16][64];
    for (int idx = threadIdx.x; idx < 16 * 64; idx += 256) {
        int bb = idx / 64, d = idx % 64;
        xa[bb][d] = ws[OFF_AGG + (i * B + bg * 16 + bb) * D + kbase + d];
        xq[bb][d] = ws[OFF_Q + (i * B + bg * 16 + bb) * D + kbase + d];
    }
    __syncthreads();
    int e = threadIdx.x;
    const float* WE = WE_w + i * D * D;
    const float* Wh = Wh_w + i * D * D;
    const float* Wc = Wqc_w + i * D * D;
    float accE[16][3], accG[16][3];
    #pragma unroll
    for (int bb = 0; bb < 16; bb++) {
        accE[bb][0] = 0.f; accE[bb][1] = 0.f; accE[bb][2] = 0.f;
        accG[bb][0] = 0.f; accG[bb][1] = 0.f; accG[bb][2] = 0.f;
    }
    for (int d2 = 0; d2 < 64; d2 += 2) {
        float we[2][3], wh[2][3], wc[2][3];
        #pragma unroll
        for (int dd = 0; dd < 2; dd++) {
            const float* r1 = WE + (kbase + d2 + dd) * D + e;
            const float* r2 = Wh + (kbase + d2 + dd) * D + e;
            const float* r3 = Wc + (kbase + d2 + dd) * D + e;
            we[dd][0] = r1[0]; we[dd][1] = r1[256]; we[dd][2] = r1[512];
            wh[dd][0] = r2[0]; wh[dd][1] = r2[256]; wh[dd][2] = r2[512];
            wc[dd][0] = r3[0]; wc[dd][1] = r3[256]; wc[dd][2] = r3[512];
        }
        #pragma unroll
        for (int bb = 0; bb < 16; bb++) {
            float a0 = xa[bb][d2], a1 = xa[bb][d2 + 1];
            float q0 = xq[bb][d2], q1 = xq[bb][d2 + 1];
            #pragma unroll
            for (int s = 0; s < 3; s++) {
                accE[bb][s] += a0 * we[0][s] + a1 * we[1][s];
                accG[bb][s] += a0 * wh[0][s] + a1 * wh[1][s] + q0 * wc[0][s] + q1 * wc[1][s];
            }
        }
    }
    #pragma unroll
    for (int bb = 0; bb < 16; bb++) {
        float* pE = ws + OFF_ARENA + kc * 73728 + (i * 32 + bg * 16 + bb) * 768 + e;
        float* pG = pE + 884736;  // 12*73728
        pE[0] = accE[bb][0]; pE[256] = accE[bb][1]; pE[512] = accE[bb][2];
        pG[0] = accG[bb][0]; pG[256] = accG[bb][1]; pG[512] = accG[bb][2];
    }
}

// reduce E/G partials + bias + relu. 144 blocks (first 72: E, rest: G).
__global__ __launch_bounds__(256) void k_red_eg(const float* WE_b, const float* Wh_b,
                                                const float* Wqc_b, float* ws) {
    int blk = blockIdx.x;
    bool isG = blk >= 72;
    int idx = (isG ? blk - 72 : blk) * 256 + threadIdx.x;
    int fidx = idx * 4;
    int i = fidx / 24576, e = fidx % 768;
    float4 a;
    const float* base = ws + OFF_ARENA + (isG ? 884736 : 0);
    if (isG) {
        float4 b0 = *(const float4*)&Wh_b[i * 768 + e];
        float4 b1 = *(const float4*)&Wqc_b[i * 768 + e];
        a = make_float4(b0.x + b1.x, b0.y + b1.y, b0.z + b1.z, b0.w + b1.w);
    } else {
        a = *(const float4*)&WE_b[i * 768 + e];
    }
    #pragma unroll
    for (int kc = 0; kc < 12; kc++) {
        float4 p = *(const float4*)&base[kc * 73728 + fidx];
        a.x += p.x; a.y += p.y; a.z += p.z; a.w += p.w;
    }
    a.x = fmaxf(a.x, 0.f); a.y = fmaxf(a.y, 0.f); a.z = fmaxf(a.z, 0.f); a.w = fmaxf(a.w, 0.f);
    *(float4*)&ws[(isG ? OFF_G : OFF_E) + fidx] = a;
}

// K5c: LayerNorm(E)*LayerNorm(G) -> fused. 96 blocks (i,b).
__global__ __launch_bounds__(256) void k_ln(const float* lnE_g, const float* lnE_b,
        const float* lnG_g, const float* lnG_b, float* ws) {
    int blk = blockIdx.x;
    int i = blk / B, b = blk % B;
    const float* E = ws + OFF_E + (i * B + b) * D;
    const float* G = ws + OFF_G + (i * B + b) * D;
    int t = threadIdx.x;
    float e0 = E[t], e1 = E[t + 256], e2 = E[t + 512];
    float g0 = G[t], g1 = G[t + 256], g2 = G[t + 512];
    __shared__ float r1[256], r2[256], r3[256], r4[256];
    r1[t] = e0 + e1 + e2;
    r2[t] = e0 * e0 + e1 * e1 + e2 * e2;
    r3[t] = g0 + g1 + g2;
    r4[t] = g0 * g0 + g1 * g1 + g2 * g2;
    __syncthreads();
    for (int st = 128; st > 0; st >>= 1) {
        if (t < st) { r1[t] += r1[t + st]; r2[t] += r2[t + st]; r3[t] += r3[t + st]; r4[t] += r4[t + st]; }
        __syncthreads();
    }
    float mE = r1[0] * (1.0f / D), vE = r2[0] * (1.0f / D) - mE * mE;
    float mG = r3[0] * (1.0f / D), vG = r4[0] * (1.0f / D) - mG * mG;
    float sE = rsqrtf(vE + LN_EPS), sG = rsqrtf(vG + LN_EPS);
    float* o = ws + OFF_FUSED + b * MD + i * D;
    const float* eg = lnE_g + i * D; const float* ebv = lnE_b + i * D;
    const float* gg = lnG_g + i * D; const float* gbv = lnG_b + i * D;
    o[t]       = ((e0 - mE) * sE * eg[t]       + ebv[t])       * ((g0 - mG) * sG * gg[t]       + gbv[t]);
    o[t + 256] = ((e1 - mE) * sE * eg[t + 256] + ebv[t + 256]) * ((g1 - mG) * sG * gg[t + 256] + gbv[t + 256]);
    o[t + 512] = ((e2 - mE) * sE * eg[t + 512] + ebv[t + 512]) * ((g2 - mG) * sG * gg[t + 512] + gbv[t + 512]);
}

// K6: Pattern A: out partials. 48 blocks (bg 2 (16 b), kc 24 (96 f)). Thread owns float4 h.
__global__ __launch_bounds__(256) void k_out(const float* out_w, float* ws) {
    int blk = blockIdx.x;
    int bg = blk / 24, kc = blk % 24;
    int kbase = kc * 96;
    __shared__ __align__(16) float xs[16][96];
    for (int idx = threadIdx.x; idx < 16 * 96; idx += 256) {
        int bb = idx / 96, d = idx % 96;
        xs[bb][d] = ws[OFF_FUSED + (bg * 16 + bb) * MD + kbase + d];
    }
    __syncthreads();
    int h4 = threadIdx.x * 4;
    float4 acc[16];
    #pragma unroll
    for (int bb = 0; bb < 16; bb++) acc[bb] = make_float4(0.f, 0.f, 0.f, 0.f);
    for (int d4 = 0; d4 < 96; d4 += 4) {
        float4 w0 = *(const float4*)&out_w[(kbase + d4 + 0) * H + h4];
        float4 w1 = *(const float4*)&out_w[(kbase + d4 + 1) * H + h4];
        float4 w2 = *(const float4*)&out_w[(kbase + d4 + 2) * H + h4];
        float4 w3 = *(const float4*)&out_w[(kbase + d4 + 3) * H + h4];
        #pragma unroll
        for (int bb = 0; bb < 16; bb++) {
            float4 x = *(const float4*)&xs[bb][d4];
            acc[bb].x += x.x * w0.x + x.y * w1.x + x.z * w2.x + x.w * w3.x;
            acc[bb].y += x.x * w0.y + x.y * w1.y + x.z * w2.y + x.w * w3.y;
            acc[bb].z += x.x * w0.z + x.y * w1.z + x.z * w2.z + x.w * w3.z;
            acc[bb].w += x.x * w0.w + x.y * w1.w + x.z * w2.w + x.w * w3.w;
        }
    }
    #pragma unroll
    for (int bb = 0; bb < 16; bb++)
        *(float4*)&ws[OFF_ARENA + (kc * 32 + bg * 16 + bb) * 1024 + h4] = acc[bb];
}

// final: sum out partials + bias, write kl. 32 blocks (b).
__global__ __launch_bounds__(256) void k_fin(const float* out_b, float* ws, float* out) {
    int b = blockIdx.x;
    int h4 = threadIdx.x * 4;
    float4 a = *(const float4*)&out_b[h4];
    #pragma unroll
    for (int kc = 0; kc < 24; kc++) {
        float4 p = *(const float4*)&ws[OFF_ARENA + (kc * 32 + b) * 1024 + h4];
        a.x += p.x; a.y += p.y; a.z += p.z; a.w += p.w;
    }
    *(float4*)&out[b * H + h4] = a;
    if (b == 0 && threadIdx.x == 0) out[B * H] = ws[OFF_KL];
}

extern "C" void kernel_launch(void* const* d_in, const int* in_sizes, int n_in,
                              void* d_out, int out_size, void* d_ws, size_t ws_size,
                              hipStream_t stream) {
    const float* feats = (const float*)d_in[0];
    const float* Wq    = (const float*)d_in[1];
    const float* bq    = (const float*)d_in[2];
    const float* Wk    = (const float*)d_in[3];
    const float* bk    = (const float*)d_in[4];
    const float* Wv    = (const float*)d_in[5];
    const float* bv    = (const float*)d_in[6];
    const float* pgq_w = (const float*)d_in[7];
    const float* pgq_b = (const float*)d_in[8];
    const float* pgk_w = (const float*)d_in[9];
    const float* pgk_b = (const float*)d_in[10];
    const float* mu_w  = (const float*)d_in[11];
    const float* mu_b  = (const float*)d_in[12];
    const float* lv_w  = (const float*)d_in[13];
    const float* lv_b  = (const float*)d_in[14];
    const float* dyn   = (const float*)d_in[15];
    const float* WE_w  = (const float*)d_in[16];
    const float* WE_b  = (const float*)d_in[17];
    const float* Wh_w  = (const float*)d_in[18];
    const float* Wh_b  = (const float*)d_in[19];
    const float* Wqc_w = (const float*)d_in[20];
    const float* Wqc_b = (const float*)d_in[21];
    const float* lnE_g = (const float*)d_in[22];
    const float* lnE_b = (const float*)d_in[23];
    const float* lnG_g = (const float*)d_in[24];
    const float* lnG_b = (const float*)d_in[25];
    const float* out_w = (const float*)d_in[26];
    const float* out_b = (const float*)d_in[27];
    const float* eps   = (const float*)d_in[28];
    float* ws  = (float*)d_ws;
    float* out = (float*)d_out;

    hipMemsetAsync((char*)d_ws + OFF_KL * sizeof(float), 0, sizeof(float), stream);

    k_prep<<<519, 256, 0, stream>>>(Wq, Wk, bq, bk, mu_w, mu_b, lv_w, lv_b,
                                    pgq_w, pgq_b, pgk_w, pgk_b, ws);
    k_stats<<<1536, 256, 0, stream>>>(feats, ws);
    k_qrow<<<96, 256, 0, stream>>>(feats, Wq, ws);
    k_red_q<<<96, 256, 0, stream>>>(bq, bk, ws);
    k_qk<<<96, 256, 0, stream>>>(ws);
    k_red_qk<<<144, 256, 0, stream>>>(ws);
    k_score<<<384, 256, 0, stream>>>(feats, ws);
    k_wsum<<<288, 256, 0, stream>>>(feats, eps, dyn, ws);
    k_agg<<<96, 256, 0, stream>>>(Wv, ws);
    k_red_agg<<<72, 256, 0, stream>>>(bv, ws);
    k_eg<<<72, 256, 0, stream>>>(WE_w, Wh_w, Wqc_w, ws);
    k_red_eg<<<144, 256, 0, stream>>>(WE_b, Wh_b, Wqc_b, ws);
    k_ln<<<M * B, 256, 0, stream>>>(lnE_g, lnE_b, lnG_g, lnG_b, ws);
    k_out<<<48, 256, 0, stream>>>(out_w, ws);
    k_fin<<<32, 256, 0, stream>>>(out_b, ws, out);
}

// Round 5
// 360.856 us; speedup vs baseline: 6.5902x; 1.1826x over previous
//
#include <hip/hip_runtime.h>

// Problem constants (fixed by the reference)
#define M 3
#define B 32
#define S 256
#define D 768
#define H 1024
#define MD (M * D)          // 2304
#define NP (M * (M - 1))    // 6 ordered (i,j) pairs
#define SCALE 0.03608439182435161f  // 1/sqrt(768)
#define LN_EPS 1e-5f

// Workspace layout (float offsets). Total 4312704 floats = ~17.3 MB.
#define OFF_WMU   0         // [M][D]
#define OFF_WLV   2304      // [M][D]
#define OFF_WPGQ  4608      // [M][D]
#define OFF_WPK   6912      // [NP][D]
#define OFF_CMU   11520     // [M]
#define OFF_CLV   11523     // [M]
#define OFF_CPGQ  11526     // [M]
#define OFF_CPK   11529     // [NP]
#define OFF_MU    11552     // [M][B][S]
#define OFF_LV    36128     // [M][B][S]
#define OFF_PKPRE 60704     // [NP][B][S]
#define OFF_PQPRE 109856    // [M][B]
#define OFF_Q     109952    // [M][B][D]
#define OFF_QBK   183680    // [NP][B]
#define OFF_QK    183872    // [NP][B][D]
#define OFF_FSUM  331328    // [NP][B][D]
#define OFF_AGG   478784    // [M][B][D]
#define OFF_E     552512    // [M][B][D]
#define OFF_G     626240    // [M][B][D]
#define OFF_FUSED 699968    // [B][MD]
#define OFF_KL    773696    // [1]
#define OFF_WKT   773760    // [M][D][D] Wk transposed (1769472 floats)
#define OFF_ARENA 2543232   // k-split partials / raw scores (max 1769472 floats)

__device__ __forceinline__ float wave_reduce(float v) {
    #pragma unroll
    for (int o = 32; o > 0; o >>= 1) v += __shfl_down(v, o, 64);
    return v;
}

__device__ __forceinline__ float sigmoidf(float x) {
    return 1.0f / (1.0f + __expf(-x));
}

__device__ __forceinline__ float dot4(float4 a, float4 b) {
    return a.x * b.x + a.y * b.y + a.z * b.z + a.w * b.w;
}

__device__ __forceinline__ void fma4(float4& a, float s, float4 w) {
    a.x += s * w.x; a.y += s * w.y; a.z += s * w.z; a.w += s * w.w;
}

// K0: fused prep: blocks 0..71 vector-dots, 72..86 scalar consts, 87..518 Wk transpose.
__global__ __launch_bounds__(256) void k_prep(const float* Wq, const float* Wk,
        const float* bq, const float* bk,
        const float* mu_w, const float* mu_b, const float* lv_w, const float* lv_b,
        const float* pgq_w, const float* pgq_b, const float* pgk_w, const float* pgk_b,
        float* ws) {
    int blk = blockIdx.x;
    if (blk < 72) {
        int mat = blk / 12, rg = blk % 12;
        const float* Wm; const float *va, *vb, *vc;
        float *oa, *ob, *oc; int nv;
        if (mat < 3) {
            int i = mat;
            Wm = Wq + i * D * D;
            va = mu_w + i * D; vb = lv_w + i * D; vc = pgq_w + i * D;
            oa = ws + OFF_WMU + i * D; ob = ws + OFF_WLV + i * D; oc = ws + OFF_WPGQ + i * D;
            nv = 3;
        } else {
            int j = mat - 3;
            int i1 = (j == 0) ? 1 : 0, i2 = (j == 2) ? 1 : 2;
            int p1 = 2 * i1 + ((j < i1) ? j : j - 1);
            int p2 = 2 * i2 + ((j < i2) ? j : j - 1);
            Wm = Wk + j * D * D;
            va = pgk_w + i1 * D; vb = pgk_w + i2 * D; vc = va;
            oa = ws + OFF_WPK + p1 * D; ob = ws + OFF_WPK + p2 * D; oc = oa;
            nv = 2;
        }
        int wave = threadIdx.x >> 6, lane = threadIdx.x & 63;
        const float4* va4 = (const float4*)va;
        const float4* vb4 = (const float4*)vb;
        const float4* vc4 = (const float4*)vc;
        float4 A0 = va4[lane], A1 = va4[lane + 64], A2 = va4[lane + 128];
        float4 B0 = vb4[lane], B1 = vb4[lane + 64], B2 = vb4[lane + 128];
        float4 C0 = vc4[lane], C1 = vc4[lane + 64], C2 = vc4[lane + 128];
        int base = rg * 64 + wave * 16;
        for (int r = 0; r < 16; r += 2) {
            const float4* rowP = (const float4*)(Wm + (base + r) * D);
            const float4* rowQ = (const float4*)(Wm + (base + r + 1) * D);
            float4 x0 = rowP[lane], x1 = rowP[lane + 64], x2 = rowP[lane + 128];
            float4 y0 = rowQ[lane], y1 = rowQ[lane + 64], y2 = rowQ[lane + 128];
            float daP = dot4(x0, A0) + dot4(x1, A1) + dot4(x2, A2);
            float dbP = dot4(x0, B0) + dot4(x1, B1) + dot4(x2, B2);
            float dcP = dot4(x0, C0) + dot4(x1, C1) + dot4(x2, C2);
            float daQ = dot4(y0, A0) + dot4(y1, A1) + dot4(y2, A2);
            float dbQ = dot4(y0, B0) + dot4(y1, B1) + dot4(y2, B2);
            float dcQ = dot4(y0, C0) + dot4(y1, C1) + dot4(y2, C2);
            daP = wave_reduce(daP); dbP = wave_reduce(dbP);
            daQ = wave_reduce(daQ); dbQ = wave_reduce(dbQ);
            if (nv == 3) { dcP = wave_reduce(dcP); dcQ = wave_reduce(dcQ); }
            if (lane == 0) {
                oa[base + r] = daP; ob[base + r] = dbP;
                oa[base + r + 1] = daQ; ob[base + r + 1] = dbQ;
                if (nv == 3) { oc[base + r] = dcP; oc[base + r + 1] = dcQ; }
            }
        }
    } else if (blk < 87) {
        int job = blk - 72;
        const float *a, *bvec; float bias; float* out;
        if (job < 3)      { int i = job;     a = bq + i * D; bvec = mu_w + i * D;  bias = mu_b[i];  out = ws + OFF_CMU + i; }
        else if (job < 6) { int i = job - 3; a = bq + i * D; bvec = lv_w + i * D;  bias = lv_b[i];  out = ws + OFF_CLV + i; }
        else if (job < 9) { int i = job - 6; a = bq + i * D; bvec = pgq_w + i * D; bias = pgq_b[i]; out = ws + OFF_CPGQ + i; }
        else {
            int p = job - 9, i = p / 2, c = p % 2, j = c + (c >= i ? 1 : 0);
            a = bk + j * D; bvec = pgk_w + i * D; bias = pgk_b[i]; out = ws + OFF_CPK + p;
        }
        int t = threadIdx.x;
        float part = 0.f;
        if (t < 192) part = dot4(((const float4*)a)[t], ((const float4*)bvec)[t]);
        part = wave_reduce(part);
        __shared__ float r[4];
        if ((t & 63) == 0) r[t >> 6] = part;
        __syncthreads();
        if (t == 0) *out = r[0] + r[1] + r[2] + r[3] + bias;
    } else {
        int r = blk - 87;
        int j = r / 144; r = r % 144;
        int d0 = (r / 12) * 64, e0 = (r % 12) * 64;
        __shared__ float tile[64][65];
        const float* src = Wk + j * D * D;
        for (int idx = threadIdx.x; idx < 4096; idx += 256) {
            int rr = idx / 64, cc = idx % 64;
            tile[rr][cc] = src[(d0 + rr) * D + e0 + cc];
        }
        __syncthreads();
        float* dst = ws + OFF_WKT + j * D * D;
        for (int idx = threadIdx.x; idx < 4096; idx += 256) {
            int rr = idx / 64, cc = idx % 64;
            dst[(e0 + rr) * D + d0 + cc] = tile[cc][rr];
        }
    }
}

// K1: full feats pass: mu/lv/pkpre/pqpre + KL. 1536 blocks; wave owns 4 rows (ILP).
__global__ __launch_bounds__(256) void k_stats(const float* feats, float* ws) {
    __shared__ float klred[4];
    int wave = threadIdx.x >> 6, lane = threadIdx.x & 63;
    int m = blockIdx.x / 512;
    int row0 = blockIdx.x * 16 + wave * 4;
    int i1 = (m == 0) ? 1 : 0, i2 = (m == 2) ? 1 : 2;
    int p0 = 2 * i1 + ((m < i1) ? m : m - 1);
    int p1 = 2 * i2 + ((m < i2) ? m : m - 1);
    const float4* wmu  = (const float4*)(ws + OFF_WMU + m * D);
    const float4* wlv  = (const float4*)(ws + OFF_WLV + m * D);
    const float4* wpgq = (const float4*)(ws + OFF_WPGQ + m * D);
    const float4* wpk0 = (const float4*)(ws + OFF_WPK + p0 * D);
    const float4* wpk1 = (const float4*)(ws + OFF_WPK + p1 * D);
    float4 U0 = wmu[lane],  U1 = wmu[lane + 64],  U2 = wmu[lane + 128];
    float4 L0 = wlv[lane],  L1 = wlv[lane + 64],  L2 = wlv[lane + 128];
    float4 Q0 = wpgq[lane], Q1 = wpgq[lane + 64], Q2 = wpgq[lane + 128];
    float4 P0 = wpk0[lane], P1 = wpk0[lane + 64], P2 = wpk0[lane + 128];
    float4 R0 = wpk1[lane], R1 = wpk1[lane + 64], R2 = wpk1[lane + 128];
    float4 x[4][3];
    #pragma unroll
    for (int rr = 0; rr < 4; rr++) {
        const float4* f = (const float4*)(feats + (size_t)(row0 + rr) * D);
        x[rr][0] = f[lane]; x[rr][1] = f[lane + 64]; x[rr][2] = f[lane + 128];
    }
    float amu[4], alv[4], apgq[4], apk0[4], apk1[4];
    #pragma unroll
    for (int rr = 0; rr < 4; rr++) {
        amu[rr]  = dot4(x[rr][0], U0) + dot4(x[rr][1], U1) + dot4(x[rr][2], U2);
        alv[rr]  = dot4(x[rr][0], L0) + dot4(x[rr][1], L1) + dot4(x[rr][2], L2);
        apgq[rr] = dot4(x[rr][0], Q0) + dot4(x[rr][1], Q1) + dot4(x[rr][2], Q2);
        apk0[rr] = dot4(x[rr][0], P0) + dot4(x[rr][1], P1) + dot4(x[rr][2], P2);
        apk1[rr] = dot4(x[rr][0], R0) + dot4(x[rr][1], R1) + dot4(x[rr][2], R2);
    }
    #pragma unroll
    for (int rr = 0; rr < 4; rr++) {
        amu[rr] = wave_reduce(amu[rr]);  alv[rr] = wave_reduce(alv[rr]);
        apgq[rr] = wave_reduce(apgq[rr]);
        apk0[rr] = wave_reduce(apk0[rr]); apk1[rr] = wave_reduce(apk1[rr]);
    }
    if (lane == 0) {
        float cmu = ws[OFF_CMU + m], clv = ws[OFF_CLV + m];
        float cpgq = ws[OFF_CPGQ + m];
        float cpk0 = ws[OFF_CPK + p0], cpk1 = ws[OFF_CPK + p1];
        float klsum = 0.f;
        #pragma unroll
        for (int rr = 0; rr < 4; rr++) {
            int row = row0 + rr;
            int rem = row % (B * S);
            int b = rem / S, s = rem % S;
            float muv = amu[rr] + cmu;
            float lvv = alv[rr] + clv;
            ws[OFF_MU + row] = muv;
            ws[OFF_LV + row] = lvv;
            ws[OFF_PKPRE + (p0 * B + b) * S + s] = apk0[rr] + cpk0;
            ws[OFF_PKPRE + (p1 * B + b) * S + s] = apk1[rr] + cpk1;
            if (s == 0) ws[OFF_PQPRE + m * B + b] = apgq[rr] + cpgq;
            klsum += 1.0f + lvv - muv * muv - __expf(lvv);
        }
        klred[wave] = klsum;
    }
    __syncthreads();
    if (threadIdx.x == 0)
        atomicAdd(ws + OFF_KL, -(klred[0] + klred[1] + klred[2] + klred[3]));
}

// ---- GEMV v2 family: 192 threads, thread owns float4 of e, 8 batch rows ----

// K2: Q partials. 288 blocks (i 3, bg 4 (8 b), kc 24 (32 k)).
__global__ __launch_bounds__(192) void k_qrow(const float* feats, const float* Wq, float* ws) {
    int blk = blockIdx.x;
    int i = blk / 96, r = blk % 96, bg = r / 24, kc = r % 24;
    int kbase = kc * 32;
    __shared__ __align__(16) float xs[32][8];
    for (int idx = threadIdx.x; idx < 256; idx += 192) {
        int d = idx / 8, bb = idx % 8;
        xs[d][bb] = feats[((size_t)(i * B + bg * 8 + bb) * S) * D + kbase + d];
    }
    __syncthreads();
    int e4 = threadIdx.x * 4;
    const float* Wm = Wq + i * D * D + kbase * D + e4;
    float4 acc[8];
    #pragma unroll
    for (int bb = 0; bb < 8; bb++) acc[bb] = make_float4(0.f, 0.f, 0.f, 0.f);
    for (int k = 0; k < 32; k++) {
        float4 w = *(const float4*)(Wm + k * D);
        float4 x0 = *(const float4*)&xs[k][0];
        float4 x1 = *(const float4*)&xs[k][4];
        fma4(acc[0], x0.x, w); fma4(acc[1], x0.y, w);
        fma4(acc[2], x0.z, w); fma4(acc[3], x0.w, w);
        fma4(acc[4], x1.x, w); fma4(acc[5], x1.y, w);
        fma4(acc[6], x1.z, w); fma4(acc[7], x1.w, w);
    }
    #pragma unroll
    for (int bb = 0; bb < 8; bb++)
        *(float4*)&ws[OFF_ARENA + kc * 73728 + (i * 32 + bg * 8 + bb) * 768 + e4] = acc[bb];
}

// reduce Q partials (24 kc) + bias; also qbk for both pairs. 96 blocks (i,b).
__global__ __launch_bounds__(256) void k_red_q(const float* bq, const float* bk, float* ws) {
    int blk = blockIdx.x;
    int i = blk / B, b = blk % B;
    int fbase = (i * B + b) * D;
    int t = threadIdx.x;
    __shared__ float4 qsh[192];
    __shared__ float redsh[8];
    if (t < 192) {
        float4 a = *(const float4*)&bq[i * D + t * 4];
        #pragma unroll
        for (int kc = 0; kc < 24; kc++) {
            float4 v = *(const float4*)&ws[OFF_ARENA + kc * 73728 + fbase + t * 4];
            a.x += v.x; a.y += v.y; a.z += v.z; a.w += v.w;
        }
        *(float4*)&ws[OFF_Q + fbase + t * 4] = a;
        qsh[t] = a;
    }
    __syncthreads();
    int jA = (i == 0) ? 1 : 0, jB = (i == 2) ? 1 : 2;
    float pA_ = 0.f, pB_ = 0.f;
    if (t < 192) {
        float4 q = qsh[t];
        pA_ = dot4(q, *(const float4*)&bk[jA * D + t * 4]);
        pB_ = dot4(q, *(const float4*)&bk[jB * D + t * 4]);
    }
    pA_ = wave_reduce(pA_); pB_ = wave_reduce(pB_);
    int wave = t >> 6, lane = t & 63;
    if (lane == 0) { redsh[wave] = pA_; redsh[4 + wave] = pB_; }
    __syncthreads();
    if (t == 0) {
        ws[OFF_QBK + (2 * i) * B + b]     = redsh[0] + redsh[1] + redsh[2] + redsh[3];
        ws[OFF_QBK + (2 * i + 1) * B + b] = redsh[4] + redsh[5] + redsh[6] + redsh[7];
    }
}

// K3: qk partials with WkT. 288 blocks (j 3, vg 8 (8 qvecs), kc 12 (64 k)).
__global__ __launch_bounds__(192) void k_qk(float* ws) {
    int blk = blockIdx.x;
    int j = blk / 96, r = blk % 96, vg = r / 12, kc = r % 12;
    int kbase = kc * 64;
    int i1 = (j == 0) ? 1 : 0, i2 = (j == 2) ? 1 : 2;
    __shared__ __align__(16) float xs[64][8];
    for (int idx = threadIdx.x; idx < 512; idx += 192) {
        int d = idx / 8, v = idx % 8;
        int v64 = vg * 8 + v;
        int i_ = (v64 < 32) ? i1 : i2, b = v64 & 31;
        xs[d][v] = ws[OFF_Q + (i_ * 32 + b) * 768 + kbase + d];
    }
    __syncthreads();
    int e4 = threadIdx.x * 4;
    const float* Wm = ws + OFF_WKT + j * D * D + kbase * D + e4;
    float4 acc[8];
    #pragma unroll
    for (int bb = 0; bb < 8; bb++) acc[bb] = make_float4(0.f, 0.f, 0.f, 0.f);
    for (int k = 0; k < 64; k++) {
        float4 w = *(const float4*)(Wm + k * D);
        float4 x0 = *(const float4*)&xs[k][0];
        float4 x1 = *(const float4*)&xs[k][4];
        fma4(acc[0], x0.x, w); fma4(acc[1], x0.y, w);
        fma4(acc[2], x0.z, w); fma4(acc[3], x0.w, w);
        fma4(acc[4], x1.x, w); fma4(acc[5], x1.y, w);
        fma4(acc[6], x1.z, w); fma4(acc[7], x1.w, w);
    }
    #pragma unroll
    for (int v = 0; v < 8; v++)
        *(float4*)&ws[OFF_ARENA + kc * 147456 + (j * 64 + vg * 8 + v) * 768 + e4] = acc[v];
}

// reduce qk partials (12 kc) -> QK[p][b][d]. 144 blocks.
__global__ __launch_bounds__(256) void k_red_qk(float* ws) {
    int idx = blockIdx.x * 256 + threadIdx.x;
    int fidx = idx * 4;
    int p = fidx / 24576, rem = fidx % 24576;
    int b = rem / 768, d = rem % 768;
    int i = p / 2, c = p % 2, j = c + (c >= i ? 1 : 0);
    int i1 = (j == 0) ? 1 : 0;
    int iidx = (i == i1) ? 0 : 1;
    int vg = iidx * 32 + b;
    float4 a = make_float4(0.f, 0.f, 0.f, 0.f);
    #pragma unroll
    for (int kc = 0; kc < 12; kc++) {
        float4 pp = *(const float4*)&ws[OFF_ARENA + kc * 147456 + (j * 64 + vg) * 768 + d];
        a.x += pp.x; a.y += pp.y; a.z += pp.z; a.w += pp.w;
    }
    *(float4*)&ws[OFF_QK + fidx] = a;
}

// K4a: raw attention dots for both p's sharing (j,b). 384 blocks (j, b, kc 4).
__global__ __launch_bounds__(256) void k_score(const float* feats, float* ws) {
    int blk = blockIdx.x;
    int j = blk / 128, r = blk % 128, b = r / 4, kc = r % 4;
    int i1 = (j == 0) ? 1 : 0, i2 = (j == 2) ? 1 : 2;
    int pA = 2 * i1 + ((j < i1) ? j : j - 1);
    int pB = 2 * i2 + ((j < i2) ? j : j - 1);
    int wave = threadIdx.x >> 6, lane = threadIdx.x & 63;
    const float4* qa4 = (const float4*)(ws + OFF_QK + (pA * B + b) * D);
    const float4* qb4 = (const float4*)(ws + OFF_QK + (pB * B + b) * D);
    float4 qA0 = qa4[lane], qA1 = qa4[lane + 64], qA2 = qa4[lane + 128];
    float4 qB0 = qb4[lane], qB1 = qb4[lane + 64], qB2 = qb4[lane + 128];
    const float* fbase = feats + ((j * B + b) * S) * D;
    float* scA = ws + OFF_ARENA + ((j * B + b) * 2) * S;
    float* scB = scA + S;
    int k0 = kc * 64 + wave * 16;
    for (int k = k0; k < k0 + 16; k += 4) {
        float4 x[4][3];
        #pragma unroll
        for (int rr = 0; rr < 4; rr++) {
            const float4* f = (const float4*)(fbase + (k + rr) * D);
            x[rr][0] = f[lane]; x[rr][1] = f[lane + 64]; x[rr][2] = f[lane + 128];
        }
        float dA[4], dB[4];
        #pragma unroll
        for (int rr = 0; rr < 4; rr++) {
            dA[rr] = dot4(x[rr][0], qA0) + dot4(x[rr][1], qA1) + dot4(x[rr][2], qA2);
            dB[rr] = dot4(x[rr][0], qB0) + dot4(x[rr][1], qB1) + dot4(x[rr][2], qB2);
        }
        #pragma unroll
        for (int rr = 0; rr < 4; rr++) { dA[rr] = wave_reduce(dA[rr]); dB[rr] = wave_reduce(dB[rr]); }
        if (lane == 0) {
            #pragma unroll
            for (int rr = 0; rr < 4; rr++) { scA[k + rr] = dA[rr]; scB[k + rr] = dB[rr]; }
        }
    }
}

// K4b: gates + softmax + weighted feats sum stripe. 288 blocks (j, b, dc 3).
__global__ __launch_bounds__(256) void k_wsum(const float* feats, const float* eps,
                                              const float* dyn, float* ws) {
    int blk = blockIdx.x;
    int j = blk / 96, r = blk % 96, b = r / 3, dc = r % 3;
    int i1 = (j == 0) ? 1 : 0, i2 = (j == 2) ? 1 : 2;
    int pA = 2 * i1 + ((j < i1) ? j : j - 1);
    int pB = 2 * i2 + ((j < i2) ? j : j - 1);
    __shared__ float sA[S], sB[S], redm[256];
    int t = threadIdx.x;
    float dynv = dyn[0];
    const float* rawA = ws + OFF_ARENA + ((j * B + b) * 2) * S;
    const float* rawB = rawA + S;
    {
        float muk = ws[OFF_MU + (i1 * B + b) * S + t];
        float lvk = ws[OFF_LV + (i1 * B + b) * S + t];
        float ek  = eps[(pA * B + b) * S + t];
        float g   = sigmoidf(muk + dynv * __expf(0.5f * lvk) * ek);
        float pk  = sigmoidf(ws[OFF_PKPRE + (pA * B + b) * S + t]) * g;
        float mu0 = ws[OFF_MU + (i1 * B + b) * S];
        float lv0 = ws[OFF_LV + (i1 * B + b) * S];
        float e0  = eps[(pA * B + b) * S];
        float g0  = sigmoidf(mu0 + dynv * __expf(0.5f * lv0) * e0);
        float pq  = sigmoidf(ws[OFF_PQPRE + i1 * B + b]) * g0;
        float qbk = ws[OFF_QBK + pA * B + b];
        sA[t] = (rawA[t] + qbk) * SCALE * pq * pk;
        muk = ws[OFF_MU + (i2 * B + b) * S + t];
        lvk = ws[OFF_LV + (i2 * B + b) * S + t];
        ek  = eps[(pB * B + b) * S + t];
        g   = sigmoidf(muk + dynv * __expf(0.5f * lvk) * ek);
        pk  = sigmoidf(ws[OFF_PKPRE + (pB * B + b) * S + t]) * g;
        mu0 = ws[OFF_MU + (i2 * B + b) * S];
        lv0 = ws[OFF_LV + (i2 * B + b) * S];
        e0  = eps[(pB * B + b) * S];
        g0  = sigmoidf(mu0 + dynv * __expf(0.5f * lv0) * e0);
        pq  = sigmoidf(ws[OFF_PQPRE + i2 * B + b]) * g0;
        qbk = ws[OFF_QBK + pB * B + b];
        sB[t] = (rawB[t] + qbk) * SCALE * pq * pk;
    }
    __syncthreads();
    redm[t] = sA[t]; __syncthreads();
    for (int st = 128; st > 0; st >>= 1) { if (t < st) redm[t] = fmaxf(redm[t], redm[t + st]); __syncthreads(); }
    float mxA = redm[0]; __syncthreads();
    float wA = __expf(sA[t] - mxA);
    redm[t] = wA; __syncthreads();
    for (int st = 128; st > 0; st >>= 1) { if (t < st) redm[t] += redm[t + st]; __syncthreads(); }
    float sumA = redm[0]; __syncthreads();
    sA[t] = wA / sumA;
    __syncthreads();
    redm[t] = sB[t]; __syncthreads();
    for (int st = 128; st > 0; st >>= 1) { if (t < st) redm[t] = fmaxf(redm[t], redm[t + st]); __syncthreads(); }
    float mxB = redm[0]; __syncthreads();
    float wB = __expf(sB[t] - mxB);
    redm[t] = wB; __syncthreads();
    for (int st = 128; st > 0; st >>= 1) { if (t < st) redm[t] += redm[t + st]; __syncthreads(); }
    float sumB = redm[0]; __syncthreads();
    sB[t] = wB / sumB;
    __syncthreads();
    int dim = dc * 256 + t;
    const float* fcol = feats + ((j * B + b) * S) * D + dim;
    float accA = 0.f, accB = 0.f;
    #pragma unroll 8
    for (int k = 0; k < S; k++) {
        float fv = fcol[k * D];
        accA += sA[k] * fv;
        accB += sB[k] * fv;
    }
    ws[OFF_FSUM + (pA * B + b) * D + dim] = accA;
    ws[OFF_FSUM + (pB * B + b) * D + dim] = accB;
}

// K5a: agg partials (2 Wv fused). 288 blocks (i 3, bg 4, kc 24 (32 k)).
__global__ __launch_bounds__(192) void k_agg(const float* Wv, float* ws) {
    int blk = blockIdx.x;
    int i = blk / 96, r = blk % 96, bg = r / 24, kc = r % 24;
    int kbase = kc * 32;
    int j0 = (i == 0) ? 1 : 0, j1 = (i == 2) ? 1 : 2;
    int p0 = 2 * i, p1 = 2 * i + 1;
    __shared__ __align__(16) float xs0[32][8], xs1[32][8];
    for (int idx = threadIdx.x; idx < 256; idx += 192) {
        int d = idx / 8, bb = idx % 8;
        xs0[d][bb] = ws[OFF_FSUM + (p0 * B + bg * 8 + bb) * D + kbase + d];
        xs1[d][bb] = ws[OFF_FSUM + (p1 * B + bg * 8 + bb) * D + kbase + d];
    }
    __syncthreads();
    int e4 = threadIdx.x * 4;
    const float* W0 = Wv + j0 * D * D + kbase * D + e4;
    const float* W1 = Wv + j1 * D * D + kbase * D + e4;
    float4 acc[8];
    #pragma unroll
    for (int bb = 0; bb < 8; bb++) acc[bb] = make_float4(0.f, 0.f, 0.f, 0.f);
    for (int k = 0; k < 32; k++) {
        float4 w0 = *(const float4*)(W0 + k * D);
        float4 w1 = *(const float4*)(W1 + k * D);
        float4 a0 = *(const float4*)&xs0[k][0];
        float4 a1 = *(const float4*)&xs0[k][4];
        float4 b0 = *(const float4*)&xs1[k][0];
        float4 b1 = *(const float4*)&xs1[k][4];
        fma4(acc[0], a0.x, w0); fma4(acc[1], a0.y, w0);
        fma4(acc[2], a0.z, w0); fma4(acc[3], a0.w, w0);
        fma4(acc[4], a1.x, w0); fma4(acc[5], a1.y, w0);
        fma4(acc[6], a1.z, w0); fma4(acc[7], a1.w, w0);
        fma4(acc[0], b0.x, w1); fma4(acc[1], b0.y, w1);
        fma4(acc[2], b0.z, w1); fma4(acc[3], b0.w, w1);
        fma4(acc[4], b1.x, w1); fma4(acc[5], b1.y, w1);
        fma4(acc[6], b1.z, w1); fma4(acc[7], b1.w, w1);
    }
    #pragma unroll
    for (int bb = 0; bb < 8; bb++)
        *(float4*)&ws[OFF_ARENA + kc * 73728 + (i * 32 + bg * 8 + bb) * 768 + e4] = acc[bb];
}

// reduce agg partials (24 kc) + bv biases. 72 blocks.
__global__ __launch_bounds__(256) void k_red_agg(const float* bv, float* ws) {
    int idx = blockIdx.x * 256 + threadIdx.x;
    int fidx = idx * 4;
    int i = fidx / 24576, e = fidx % 768;
    int j0 = (i == 0) ? 1 : 0, j1 = (i == 2) ? 1 : 2;
    float4 b0 = *(const float4*)&bv[j0 * 768 + e];
    float4 b1 = *(const float4*)&bv[j1 * 768 + e];
    float4 a = make_float4(b0.x + b1.x, b0.y + b1.y, b0.z + b1.z, b0.w + b1.w);
    const float* base = ws + OFF_ARENA;
    #pragma unroll
    for (int kc = 0; kc < 24; kc++) {
        float4 p = *(const float4*)&base[kc * 73728 + fidx];
        a.x += p.x; a.y += p.y; a.z += p.z; a.w += p.w;
    }
    *(float4*)&ws[OFF_AGG + fidx] = a;
}

// K5b: E/G partials. 288 blocks (kind 2, i 3, bg 4, kc 12 (64 k)).
// kind0: E = agg@WE; kind1: G = agg@Wh + q@Wqc (fused accumulator).
__global__ __launch_bounds__(192) void k_eg(const float* WE_w, const float* Wh_w,
                                            const float* Wqc_w, float* ws) {
    int blk = blockIdx.x;
    int kind = blk / 144, r = blk % 144;
    int i = r / 48, r2 = r % 48, bg = r2 / 12, kc = r2 % 12;
    int kbase = kc * 64;
    __shared__ __align__(16) float xa[64][8], xq[64][8];
    for (int idx = threadIdx.x; idx < 512; idx += 192) {
        int d = idx / 8, bb = idx % 8;
        xa[d][bb] = ws[OFF_AGG + (i * B + bg * 8 + bb) * D + kbase + d];
        if (kind) xq[d][bb] = ws[OFF_Q + (i * B + bg * 8 + bb) * D + kbase + d];
    }
    __syncthreads();
    int e4 = threadIdx.x * 4;
    float4 acc[8];
    #pragma unroll
    for (int bb = 0; bb < 8; bb++) acc[bb] = make_float4(0.f, 0.f, 0.f, 0.f);
    if (kind == 0) {
        const float* Wm = WE_w + i * D * D + kbase * D + e4;
        for (int k = 0; k < 64; k++) {
            float4 w = *(const float4*)(Wm + k * D);
            float4 a0 = *(const float4*)&xa[k][0];
            float4 a1 = *(const float4*)&xa[k][4];
            fma4(acc[0], a0.x, w); fma4(acc[1], a0.y, w);
            fma4(acc[2], a0.z, w); fma4(acc[3], a0.w, w);
            fma4(acc[4], a1.x, w); fma4(acc[5], a1.y, w);
            fma4(acc[6], a1.z, w); fma4(acc[7], a1.w, w);
        }
    } else {
        const float* Wh = Wh_w + i * D * D + kbase * D + e4;
        const float* Wc = Wqc_w + i * D * D + kbase * D + e4;
        for (int k = 0; k < 64; k++) {
            float4 wh = *(const float4*)(Wh + k * D);
            float4 wc = *(const float4*)(Wc + k * D);
            float4 a0 = *(const float4*)&xa[k][0];
            float4 a1 = *(const float4*)&xa[k][4];
            float4 q0 = *(const float4*)&xq[k][0];
            float4 q1 = *(const float4*)&xq[k][4];
            fma4(acc[0], a0.x, wh); fma4(acc[1], a0.y, wh);
            fma4(acc[2], a0.z, wh); fma4(acc[3], a0.w, wh);
            fma4(acc[4], a1.x, wh); fma4(acc[5], a1.y, wh);
            fma4(acc[6], a1.z, wh); fma4(acc[7], a1.w, wh);
            fma4(acc[0], q0.x, wc); fma4(acc[1], q0.y, wc);
            fma4(acc[2], q0.z, wc); fma4(acc[3], q0.w, wc);
            fma4(acc[4], q1.x, wc); fma4(acc[5], q1.y, wc);
            fma4(acc[6], q1.z, wc); fma4(acc[7], q1.w, wc);
        }
    }
    int base = OFF_ARENA + (kind ? 884736 : 0) + kc * 73728;
    #pragma unroll
    for (int bb = 0; bb < 8; bb++)
        *(float4*)&ws[base + (i * 32 + bg * 8 + bb) * 768 + e4] = acc[bb];
}

// reduce E/G partials (12 kc) + bias + relu. 144 blocks (first 72: E, rest: G).
__global__ __launch_bounds__(256) void k_red_eg(const float* WE_b, const float* Wh_b,
                                                const float* Wqc_b, float* ws) {
    int blk = blockIdx.x;
    bool isG = blk >= 72;
    int idx = (isG ? blk - 72 : blk) * 256 + threadIdx.x;
    int fidx = idx * 4;
    int i = fidx / 24576, e = fidx % 768;
    float4 a;
    const float* base = ws + OFF_ARENA + (isG ? 884736 : 0);
    if (isG) {
        float4 b0 = *(const float4*)&Wh_b[i * 768 + e];
        float4 b1 = *(const float4*)&Wqc_b[i * 768 + e];
        a = make_float4(b0.x + b1.x, b0.y + b1.y, b0.z + b1.z, b0.w + b1.w);
    } else {
        a = *(const float4*)&WE_b[i * 768 + e];
    }
    #pragma unroll
    for (int kc = 0; kc < 12; kc++) {
        float4 p = *(const float4*)&base[kc * 73728 + fidx];
        a.x += p.x; a.y += p.y; a.z += p.z; a.w += p.w;
    }
    a.x = fmaxf(a.x, 0.f); a.y = fmaxf(a.y, 0.f); a.z = fmaxf(a.z, 0.f); a.w = fmaxf(a.w, 0.f);
    *(float4*)&ws[(isG ? OFF_G : OFF_E) + fidx] = a;
}

// K5c: LayerNorm(E)*LayerNorm(G) -> fused. 96 blocks (i,b).
__global__ __launch_bounds__(256) void k_ln(const float* lnE_g, const float* lnE_b,
        const float* lnG_g, const float* lnG_b, float* ws) {
    int blk = blockIdx.x;
    int i = blk / B, b = blk % B;
    const float* E = ws + OFF_E + (i * B + b) * D;
    const float* G = ws + OFF_G + (i * B + b) * D;
    int t = threadIdx.x;
    float e0 = E[t], e1 = E[t + 256], e2 = E[t + 512];
    float g0 = G[t], g1 = G[t + 256], g2 = G[t + 512];
    __shared__ float r1[256], r2[256], r3[256], r4[256];
    r1[t] = e0 + e1 + e2;
    r2[t] = e0 * e0 + e1 * e1 + e2 * e2;
    r3[t] = g0 + g1 + g2;
    r4[t] = g0 * g0 + g1 * g1 + g2 * g2;
    __syncthreads();
    for (int st = 128; st > 0; st >>= 1) {
        if (t < st) { r1[t] += r1[t + st]; r2[t] += r2[t + st]; r3[t] += r3[t + st]; r4[t] += r4[t + st]; }
        __syncthreads();
    }
    float mE = r1[0] * (1.0f / D), vE = r2[0] * (1.0f / D) - mE * mE;
    float mG = r3[0] * (1.0f / D), vG = r4[0] * (1.0f / D) - mG * mG;
    float sE = rsqrtf(vE + LN_EPS), sG = rsqrtf(vG + LN_EPS);
    float* o = ws + OFF_FUSED + b * MD + i * D;
    const float* eg = lnE_g + i * D; const float* ebv = lnE_b + i * D;
    const float* gg = lnG_g + i * D; const float* gbv = lnG_b + i * D;
    o[t]       = ((e0 - mE) * sE * eg[t]       + ebv[t])       * ((g0 - mG) * sG * gg[t]       + gbv[t]);
    o[t + 256] = ((e1 - mE) * sE * eg[t + 256] + ebv[t + 256]) * ((g1 - mG) * sG * gg[t + 256] + gbv[t + 256]);
    o[t + 512] = ((e2 - mE) * sE * eg[t + 512] + ebv[t + 512]) * ((g2 - mG) * sG * gg[t + 512] + gbv[t + 512]);
}

// K6: out partials. 144 blocks (bg 4 (8 b), kc 36 (64 f)). 256 threads own float4 of H.
__global__ __launch_bounds__(256) void k_out(const float* out_w, float* ws) {
    int blk = blockIdx.x;
    int bg = blk / 36, kc = blk % 36;
    int kbase = kc * 64;
    __shared__ __align__(16) float xs[64][8];
    for (int idx = threadIdx.x; idx < 512; idx += 256) {
        int d = idx / 8, bb = idx % 8;
        xs[d][bb] = ws[OFF_FUSED + (bg * 8 + bb) * MD + kbase + d];
    }
    __syncthreads();
    int e4 = threadIdx.x * 4;
    const float* Wm = out_w + kbase * H + e4;
    float4 acc[8];
    #pragma unroll
    for (int bb = 0; bb < 8; bb++) acc[bb] = make_float4(0.f, 0.f, 0.f, 0.f);
    for (int k = 0; k < 64; k++) {
        float4 w = *(const float4*)(Wm + k * H);
        float4 x0 = *(const float4*)&xs[k][0];
        float4 x1 = *(const float4*)&xs[k][4];
        fma4(acc[0], x0.x, w); fma4(acc[1], x0.y, w);
        fma4(acc[2], x0.z, w); fma4(acc[3], x0.w, w);
        fma4(acc[4], x1.x, w); fma4(acc[5], x1.y, w);
        fma4(acc[6], x1.z, w); fma4(acc[7], x1.w, w);
    }
    #pragma unroll
    for (int bb = 0; bb < 8; bb++)
        *(float4*)&ws[OFF_ARENA + kc * 32768 + (bg * 8 + bb) * 1024 + e4] = acc[bb];
}

// final: sum out partials (36 kc) + bias, write kl. 32 blocks (b).
__global__ __launch_bounds__(256) void k_fin(const float* out_b, float* ws, float* out) {
    int b = blockIdx.x;
    int h4 = threadIdx.x * 4;
    float4 a = *(const float4*)&out_b[h4];
    #pragma unroll
    for (int kc = 0; kc < 36; kc++) {
        float4 p = *(const float4*)&ws[OFF_ARENA + kc * 32768 + b * 1024 + h4];
        a.x += p.x; a.y += p.y; a.z += p.z; a.w += p.w;
    }
    *(float4*)&out[b * H + h4] = a;
    if (b == 0 && threadIdx.x == 0) out[B * H] = ws[OFF_KL];
}

extern "C" void kernel_launch(void* const* d_in, const int* in_sizes, int n_in,
                              void* d_out, int out_size, void* d_ws, size_t ws_size,
                              hipStream_t stream) {
    const float* feats = (const float*)d_in[0];
    const float* Wq    = (const float*)d_in[1];
    const float* bq    = (const float*)d_in[2];
    const float* Wk    = (const float*)d_in[3];
    const float* bk    = (const float*)d_in[4];
    const float* Wv    = (const float*)d_in[5];
    const float* bv    = (const float*)d_in[6];
    const float* pgq_w = (const float*)d_in[7];
    const float* pgq_b = (const float*)d_in[8];
    const float* pgk_w = (const float*)d_in[9];
    const float* pgk_b = (const float*)d_in[10];
    const float* mu_w  = (const float*)d_in[11];
    const float* mu_b  = (const float*)d_in[12];
    const float* lv_w  = (const float*)d_in[13];
    const float* lv_b  = (const float*)d_in[14];
    const float* dyn   = (const float*)d_in[15];
    const float* WE_w  = (const float*)d_in[16];
    const float* WE_b  = (const float*)d_in[17];
    const float* Wh_w  = (const float*)d_in[18];
    const float* Wh_b  = (const float*)d_in[19];
    const float* Wqc_w = (const float*)d_in[20];
    const float* Wqc_b = (const float*)d_in[21];
    const float* lnE_g = (const float*)d_in[22];
    const float* lnE_b = (const float*)d_in[23];
    const float* lnG_g = (const float*)d_in[24];
    const float* lnG_b = (const float*)d_in[25];
    const float* out_w = (const float*)d_in[26];
    const float* out_b = (const float*)d_in[27];
    const float* eps   = (const float*)d_in[28];
    float* ws  = (float*)d_ws;
    float* out = (float*)d_out;

    hipMemsetAsync((char*)d_ws + OFF_KL * sizeof(float), 0, sizeof(float), stream);

    k_prep<<<519, 256, 0, stream>>>(Wq, Wk, bq, bk, mu_w, mu_b, lv_w, lv_b,
                                    pgq_w, pgq_b, pgk_w, pgk_b, ws);
    k_stats<<<1536, 256, 0, stream>>>(feats, ws);
    k_qrow<<<288, 192, 0, stream>>>(feats, Wq, ws);
    k_red_q<<<96, 256, 0, stream>>>(bq, bk, ws);
    k_qk<<<288, 192, 0, stream>>>(ws);
    k_red_qk<<<144, 256, 0, stream>>>(ws);
    k_score<<<384, 256, 0, stream>>>(feats, ws);
    k_wsum<<<288, 256, 0, stream>>>(feats, eps, dyn, ws);
    k_agg<<<288, 192, 0, stream>>>(Wv, ws);
    k_red_agg<<<72, 256, 0, stream>>>(bv, ws);
    k_eg<<<288, 192, 0, stream>>>(WE_w, Wh_w, Wqc_w, ws);
    k_red_eg<<<144, 256, 0, stream>>>(WE_b, Wh_b, Wqc_b, ws);
    k_ln<<<M * B, 256, 0, stream>>>(lnE_g, lnE_b, lnG_g, lnG_b, ws);
    k_out<<<144, 256, 0, stream>>>(out_w, ws);
    k_fin<<<32, 256, 0, stream>>>(out_b, ws, out);
}